// Round 2
// baseline (6864.795 us; speedup 1.0000x reference)
//
#include <hip/hip_runtime.h>
#include <hip/hip_bf16.h>
#include <cstdint>
#include <cstddef>

#define L_SEQ 2048
#define BATCH 4
#define DM    512
#define DI    3072
#define NROWS (BATCH * L_SEQ)   // 8192
#define PROJW 1544              // 3*512 + 8

using bf16 = __hip_bfloat16;

// ---------------------------------------------------------------- utilities

__device__ __forceinline__ float sigmoidf_(float x) { return 1.f / (1.f + expf(-x)); }
__device__ __forceinline__ float us2f(unsigned int u) {
    union { unsigned int i; float f; } c; c.i = u << 16; return c.f;
}
__device__ __forceinline__ bf16  f2b(float f) { return __float2bfloat16(f); }
__device__ __forceinline__ float b2f(bf16 v)  { return __bfloat162float(v); }

__device__ __forceinline__ float4 ld4(const float* p) { return *(const float4*)p; }
__device__ __forceinline__ float4 ld4(const bf16* p) {
    short4 v = *(const short4*)p;
    float4 r;
    r.x = us2f((unsigned short)v.x);
    r.y = us2f((unsigned short)v.y);
    r.z = us2f((unsigned short)v.z);
    r.w = us2f((unsigned short)v.w);
    return r;
}
__device__ __forceinline__ void st1(float* p, float v) { *p = v; }
__device__ __forceinline__ void st1(bf16* p, float v)  { *p = f2b(v); }

// ---------------------------------------------------------------- residual copy
__global__ __launch_bounds__(256) void copy4_k(const float4* __restrict__ in,
                                               float4* __restrict__ out, int n) {
    int i = blockIdx.x * 256 + threadIdx.x;
    if (i < n) out[i] = in[i];
}

// ---------------------------------------------------------------- rmsnorm (row=512)
__global__ __launch_bounds__(256) void rmsnorm_k(const float* __restrict__ x,
                                                 const float* __restrict__ w,
                                                 float* __restrict__ xn) {
    int r = blockIdx.x, tid = threadIdx.x;
    const float* row = x + (size_t)r * DM;
    float v0 = row[tid], v1 = row[tid + 256];
    float q = v0 * v0 + v1 * v1;
#pragma unroll
    for (int off = 32; off; off >>= 1) q += __shfl_xor(q, off);
    __shared__ float sm[4];
    if ((tid & 63) == 0) sm[tid >> 6] = q;
    __syncthreads();
    q = sm[0] + sm[1] + sm[2] + sm[3];
    float scale = rsqrtf(q * (1.f / 512.f) + 1e-5f);
    float* orow = xn + (size_t)r * DM;
    orow[tid]       = v0 * scale * w[tid];
    orow[tid + 256] = v1 * scale * w[tid + 256];
}

// ---------------------------------------------------------------- generic GEMM
// C[m,n] = sum_k A[m*lda+k] * W[n*ldw+k] (+ bias[n]); A is f32 or bf16, C f32 or bf16.
// BM=BN=64, BK=16, 256 threads, 4x4 microtile. M % 64 == 0, K % 16 == 0, N guarded.
template <typename TA, typename TC, int BIAS>
__global__ __launch_bounds__(256) void gemm_nt(const TA* __restrict__ A, int lda,
                                               const float* __restrict__ W, int ldw,
                                               const float* __restrict__ bias,
                                               TC* __restrict__ C, int ldc,
                                               int N, int K) {
    __shared__ float As[16][68];
    __shared__ float Ws[16][68];
    const int tid = threadIdx.x;
    const int bm = blockIdx.x * 64;
    const int bn = blockIdx.y * 64;
    const int tx = tid & 15, ty = tid >> 4;
    const int lr = tid >> 2;          // 0..63
    const int lk = (tid & 3) * 4;     // 0,4,8,12

    float acc[4][4] = {};

    for (int k0 = 0; k0 < K; k0 += 16) {
        float4 av, wv;
        av = ld4(A + (size_t)(bm + lr) * lda + k0 + lk);
        int wn = bn + lr;
        if (wn < N) wv = ld4(W + (size_t)wn * ldw + k0 + lk);
        else        wv = make_float4(0.f, 0.f, 0.f, 0.f);
        __syncthreads();
        As[lk + 0][lr] = av.x; As[lk + 1][lr] = av.y;
        As[lk + 2][lr] = av.z; As[lk + 3][lr] = av.w;
        Ws[lk + 0][lr] = wv.x; Ws[lk + 1][lr] = wv.y;
        Ws[lk + 2][lr] = wv.z; Ws[lk + 3][lr] = wv.w;
        __syncthreads();
#pragma unroll
        for (int kk = 0; kk < 16; ++kk) {
            float4 af = *(const float4*)&As[kk][ty * 4];
            float4 wf = *(const float4*)&Ws[kk][tx * 4];
            float a_[4] = {af.x, af.y, af.z, af.w};
            float w_[4] = {wf.x, wf.y, wf.z, wf.w};
#pragma unroll
            for (int i = 0; i < 4; ++i)
#pragma unroll
                for (int j = 0; j < 4; ++j)
                    acc[i][j] = fmaf(a_[i], w_[j], acc[i][j]);
        }
    }
#pragma unroll
    for (int i = 0; i < 4; ++i) {
        int m = bm + ty * 4 + i;
#pragma unroll
        for (int j = 0; j < 4; ++j) {
            int n = bn + tx * 4 + j;
            if (n < N) {
                float v = acc[i][j];
                if (BIAS) v += bias[n];
                st1(&C[(size_t)m * ldc + n], v);
            }
        }
    }
}

// ---------------------------------------------------------------- causal depthwise conv3 + silu (in-place, bf16)
// one thread per (b,d) column; window kept in registers -> no cross-thread hazard.
__global__ __launch_bounds__(256) void conv_silu_inplace_k(bf16* __restrict__ x,
                                                           const float* __restrict__ cw,
                                                           const float* __restrict__ cb) {
    int tid = blockIdx.x * 256 + threadIdx.x;
    if (tid >= BATCH * DI) return;
    int b = tid / DI, d = tid % DI;
    float w0 = cw[d * 3], w1 = cw[d * 3 + 1], w2 = cw[d * 3 + 2], bias = cb[d];
    size_t base = (size_t)b * L_SEQ * DI + d;
    float xm2 = 0.f, xm1 = 0.f;
    float cur = b2f(x[base]);
    for (int l = 0; l < L_SEQ; ++l) {
        float nxt = (l + 1 < L_SEQ) ? b2f(x[base + (size_t)(l + 1) * DI]) : 0.f;
        float acc = bias + w0 * xm2 + w1 * xm1 + w2 * cur;
        float o = acc * sigmoidf_(acc);
        x[base + (size_t)l * DI] = f2b(o);
        xm2 = xm1; xm1 = cur; cur = nxt;
    }
}

// ---------------------------------------------------------------- longhorn selective scan (fused dt matvec)
// one thread per (b,d); 8 states + 32 dt weights in registers.
// reads xb (bf16, in-place -> y), z (bf16), x_dbl row (f32, broadcast across block).
__global__ __launch_bounds__(256) void longhorn_k(bf16* __restrict__ xb_y,
                                                  const bf16* __restrict__ z,
                                                  const float* __restrict__ xdbl,
                                                  const float* __restrict__ dtw,
                                                  const float* __restrict__ dtb_v,
                                                  const float* __restrict__ Dv) {
    int tid = blockIdx.x * 256 + threadIdx.x;   // 0..12287
    int b = tid / DI;
    int d = tid % DI;
    float w32[32];
#pragma unroll
    for (int i = 0; i < 32; ++i) w32[i] = dtw[d * 32 + i];
    float s[8] = {0.f, 0.f, 0.f, 0.f, 0.f, 0.f, 0.f, 0.f};
    float dtb = dtb_v[d], Dd = Dv[d];
    size_t rbase = (size_t)b * L_SEQ * DI + d;
    const float* xdb = xdbl + (size_t)b * L_SEQ * 48;

    float xv = b2f(xb_y[rbase]);
    float zv = b2f(z[rbase]);

    for (int t = 0; t < L_SEQ; ++t) {
        float x_c = xv, z_c = zv;
        if (t + 1 < L_SEQ) {
            size_t nidx = rbase + (size_t)(t + 1) * DI;
            xv = b2f(xb_y[nidx]);
            zv = b2f(z[nidx]);
        }
        const float* row = xdb + (size_t)t * 48;
        float dt_c = 0.f;
#pragma unroll
        for (int i = 0; i < 32; i += 4) {
            float4 r4 = *(const float4*)(row + i);
            dt_c = fmaf(r4.x, w32[i + 0], dt_c);
            dt_c = fmaf(r4.y, w32[i + 1], dt_c);
            dt_c = fmaf(r4.z, w32[i + 2], dt_c);
            dt_c = fmaf(r4.w, w32[i + 3], dt_c);
        }
        float kq[16];
#pragma unroll
        for (int i = 0; i < 16; i += 4) *(float4*)&kq[i] = *(const float4*)(row + 32 + i);

        float sig = sigmoidf_(dt_c + dtb);
        float ksq = 0.f;
#pragma unroll
        for (int n = 0; n < 8; ++n) ksq = fmaf(kq[n], kq[n], ksq);
        float dts = sig / (1.f + sig * ksq);
        float y = 0.f;
#pragma unroll
        for (int n = 0; n < 8; ++n) {
            float dB = dts * kq[n];
            s[n] = s[n] * (1.f - dB * kq[n]) + x_c * dB;
            y = fmaf(s[n], kq[8 + n], y);
        }
        y = fmaf(Dd, x_c, y);
        float out = y * (z_c * sigmoidf_(z_c));
        xb_y[rbase + (size_t)t * DI] = f2b(out);
    }
}

// ---------------------------------------------------------------- TTT scan
// one wave (64 threads) per (b,h). lane g owns W[:,g] (64 VGPRs).
// exact identity: Z1q = Z1 - eta*(sum(xk^2)+1)*grad  (no 2nd matvec).
__global__ __launch_bounds__(64) void ttt_k(const bf16* __restrict__ proj,
                                            const float* __restrict__ lr_bias,
                                            const float* __restrict__ W1,
                                            const float* __restrict__ b1,
                                            const float* __restrict__ tok_idx,
                                            const float* __restrict__ tok_bias,
                                            const float* __restrict__ ln_w,
                                            const float* __restrict__ ln_b,
                                            float* __restrict__ xqw) {
    const int lane = threadIdx.x;
    const int bh = blockIdx.x;
    const int b = bh >> 3, h = bh & 7;
    __shared__ float sxk[64];

    float W[64];
#pragma unroll
    for (int f = 0; f < 64; ++f) W[f] = W1[(size_t)(h * 64 + f) * 64 + lane];
    float bb = b1[h * 64 + lane];
    float lw = ln_w[h * 64 + lane];
    float lb = ln_b[h * 64 + lane];
    float lrb = lr_bias[h];

    const bf16* pb = proj + (size_t)b * L_SEQ * PROJW;
    float xk = b2f(pb[h * 64 + lane]);
    float xv = b2f(pb[512 + h * 64 + lane]);
    float lr = b2f(pb[1536 + h]);

    for (int t = 0; t < L_SEQ; ++t) {
        float xk_c = xk, xv_c = xv, lr_c = lr;
        if (t + 1 < L_SEQ) {
            const bf16* pr = pb + (size_t)(t + 1) * PROJW;
            xk = b2f(pr[h * 64 + lane]);
            xv = b2f(pr[512 + h * 64 + lane]);
            lr = b2f(pr[1536 + h]);
        }
        float tok = fmaxf(tok_idx[t] + tok_bias[t], 0.f);

        sxk[lane] = xk_c;
        __syncthreads();

        // matvec Z1 = xk @ W + b
        float z1 = bb;
        float k2 = xk_c * xk_c;
#pragma unroll
        for (int fb = 0; fb < 16; ++fb) {
            float4 kv = *(const float4*)&sxk[fb * 4];
            z1 = fmaf(kv.x, W[fb * 4 + 0], z1);
            z1 = fmaf(kv.y, W[fb * 4 + 1], z1);
            z1 = fmaf(kv.z, W[fb * 4 + 2], z1);
            z1 = fmaf(kv.w, W[fb * 4 + 3], z1);
        }
        // butterfly 1: {k2, S1, S2}
        float s1 = z1, s2 = z1 * z1;
#pragma unroll
        for (int off = 32; off; off >>= 1) {
            k2 += __shfl_xor(k2, off);
            s1 += __shfl_xor(s1, off);
            s2 += __shfl_xor(s2, off);
        }
        float mu = s1 * (1.f / 64.f);
        float var = s2 * (1.f / 64.f) - mu * mu;
        float istd = rsqrtf(var + 1e-6f);
        float xh = (z1 - mu) * istd;
        float go = lw * xh + lb - (xv_c - xk_c);
        float gxh = go * lw;
        // butterfly 2: {A, B}
        float A = gxh, Bv = gxh * xh;
#pragma unroll
        for (int off = 32; off; off >>= 1) {
            A += __shfl_xor(A, off);
            Bv += __shfl_xor(Bv, off);
        }
        float grad = (64.f * gxh - A - xh * Bv) * (istd * (1.f / 64.f));
        float eta = sigmoidf_(lr_c + lrb) * tok;
        float c1 = eta * grad;

        // rank-1 W update
#pragma unroll
        for (int fb = 0; fb < 16; ++fb) {
            float4 kv = *(const float4*)&sxk[fb * 4];
            W[fb * 4 + 0] = fmaf(-c1, kv.x, W[fb * 4 + 0]);
            W[fb * 4 + 1] = fmaf(-c1, kv.y, W[fb * 4 + 1]);
            W[fb * 4 + 2] = fmaf(-c1, kv.z, W[fb * 4 + 2]);
            W[fb * 4 + 3] = fmaf(-c1, kv.w, W[fb * 4 + 3]);
        }
        bb -= c1;

        // Z1q via exact shortcut
        float z1q = z1 - eta * (k2 + 1.f) * grad;
        float t1 = z1q, t2 = z1q * z1q;
#pragma unroll
        for (int off = 32; off; off >>= 1) {
            t1 += __shfl_xor(t1, off);
            t2 += __shfl_xor(t2, off);
        }
        float mu2 = t1 * (1.f / 64.f);
        float var2 = t2 * (1.f / 64.f) - mu2 * mu2;
        float istd2 = rsqrtf(var2 + 1e-6f);
        float outv = xk_c + lw * (z1q - mu2) * istd2 + lb;
        xqw[((size_t)b * L_SEQ + t) * DM + h * 64 + lane] = outv;
        __syncthreads();
    }
}

// ---------------------------------------------------------------- post-norm + gelu gate
__global__ __launch_bounds__(256) void gated_k(const float* __restrict__ xqw,
                                               const bf16* __restrict__ proj,
                                               const float* __restrict__ pnw,
                                               const float* __restrict__ pnb,
                                               float* __restrict__ gated) {
    int r = blockIdx.x, tid = threadIdx.x;
    const float* row = xqw + (size_t)r * DM;
    float v0 = row[tid], v1 = row[tid + 256];
    float s = v0 + v1, q = v0 * v0 + v1 * v1;
#pragma unroll
    for (int off = 32; off; off >>= 1) {
        s += __shfl_xor(s, off);
        q += __shfl_xor(q, off);
    }
    __shared__ float sm[8];
    if ((tid & 63) == 0) { sm[tid >> 6] = s; sm[4 + (tid >> 6)] = q; }
    __syncthreads();
    s = sm[0] + sm[1] + sm[2] + sm[3];
    q = sm[4] + sm[5] + sm[6] + sm[7];
    float mu = s * (1.f / 512.f);
    float var = q * (1.f / 512.f) - mu * mu;
    float istd = rsqrtf(var + 1e-5f);
    const bf16* grow = proj + (size_t)r * PROJW + 1024;
    float* orow = gated + (size_t)r * DM;
#pragma unroll
    for (int e = 0; e < 2; ++e) {
        int c = tid + e * 256;
        float xv = (e == 0) ? v0 : v1;
        float nv = (xv - mu) * istd * pnw[c] + pnb[c];
        float g = b2f(grow[c]);
        float gg = 0.5f * g * (1.f + tanhf(0.7978845608028654f * (g + 0.044715f * g * g * g)));
        orow[c] = gg * nv;
    }
}

// ---------------------------------------------------------------- gq mean over L
__global__ __launch_bounds__(256) void mean_k(const float* __restrict__ gq,
                                              float* __restrict__ gqm) {
    int t = blockIdx.x * 256 + threadIdx.x;  // 0..2047
    int b = t >> 9, d = t & 511;
    const float* p = gq + (size_t)b * L_SEQ * DM + d;
    float acc = 0.f;
    for (int l = 0; l < L_SEQ; ++l) acc += p[(size_t)l * DM];
    gqm[t] = acc * (1.f / (float)L_SEQ);
}

// ---------------------------------------------------------------- gain + final mix
__global__ __launch_bounds__(64) void final_k(const float* __restrict__ zl,
                                              const float* __restrict__ zt,
                                              const float* __restrict__ gk,
                                              const float* __restrict__ gqm,
                                              const float* __restrict__ alpha,
                                              const float* __restrict__ beta,
                                              float* __restrict__ out,
                                              float* __restrict__ gain_out) {
    int r = blockIdx.x;          // 0..8191
    int lane = threadIdx.x;
    int b = r >> 11;
    const float* gkr = gk + (size_t)r * DM;
    const float* gmb = gqm + b * DM;
    float acc = 0.f;
#pragma unroll
    for (int i = 0; i < 8; ++i) acc = fmaf(gmb[lane + 64 * i], gkr[lane + 64 * i], acc);
#pragma unroll
    for (int off = 32; off; off >>= 1) acc += __shfl_xor(acc, off);
    float score = acc * 0.04419417382415922f;   // 1/sqrt(512)
    float g = sigmoidf_(alpha[0] * score + beta[0]);
    g = fminf(g, 0.55f);
    if (lane == 0) gain_out[r] = g;
    const float* zlr = zl + (size_t)r * DM;
    const float* ztr = zt + (size_t)r * DM;
    float* orow = out + (size_t)r * DM;
#pragma unroll
    for (int i = 0; i < 8; ++i) {
        int c = lane + 64 * i;
        float a = zlr[c];
        orow[c] = a + g * (ztr[c] - a);
    }
}

// ---------------------------------------------------------------- host launcher

extern "C" void kernel_launch(void* const* d_in, const int* in_sizes, int n_in,
                              void* d_out, int out_size, void* d_ws, size_t ws_size,
                              hipStream_t stream) {
    const float* x           = (const float*)d_in[0];
    const float* norm_w      = (const float*)d_in[1];
    const float* in_proj_w   = (const float*)d_in[2];
    const float* conv_w      = (const float*)d_in[3];
    const float* conv_b      = (const float*)d_in[4];
    const float* x_proj_w    = (const float*)d_in[5];
    const float* dt_head_w   = (const float*)d_in[6];
    const float* dt_head_b   = (const float*)d_in[7];
    const float* Dvec        = (const float*)d_in[8];
    const float* reduce_w    = (const float*)d_in[9];
    const float* q_net_w     = (const float*)d_in[10];
    const float* gain_q_w    = (const float*)d_in[11];
    const float* gain_k_w    = (const float*)d_in[12];
    const float* alpha       = (const float*)d_in[13];
    const float* beta        = (const float*)d_in[14];
    const float* qkv_w       = (const float*)d_in[15];
    const float* qkv_b       = (const float*)d_in[16];
    const float* ttt_lr_bias = (const float*)d_in[17];
    const float* W1          = (const float*)d_in[18];
    const float* b1          = (const float*)d_in[19];
    const float* token_idx   = (const float*)d_in[20];
    const float* token_bias  = (const float*)d_in[21];
    const float* ttt_ln_w    = (const float*)d_in[22];
    const float* ttt_ln_b    = (const float*)d_in[23];
    const float* post_norm_w = (const float*)d_in[24];
    const float* post_norm_b = (const float*)d_in[25];
    const float* wo_w        = (const float*)d_in[26];
    const float* wo_b        = (const float*)d_in[27];

    const size_t SZ_ROWDM = (size_t)NROWS * DM;   // 4,194,304 elements

    float* out_p  = (float*)d_out;                 // (B,L,DM)
    float* res_p  = out_p + SZ_ROWDM;              // residual
    float* gain_p = out_p + 2 * SZ_ROWDM;          // (B*L)

    // Workspace byte layout (total need ~114.1 MB):
    //  [0,16M)      W0: xn f32 -> later h_red f32
    //  [16M,64M)    W1: xx/xb/y bf16 (48M) -> later proj bf16 [16M,~40.2M),
    //                   xqw f32 [42M,58M) -> later z_ttt [16M,32M), gq [32M,48M), gk [48M,64M)
    //  [64M,112M)   W2: z bf16 (48M) -> later gated [64M,80M), chid [80M,96M), z_long [96M,112M)
    //  [112M,113.5M) x_dbl f32
    //  [114M,+8K)   gq_mean f32
    char* base = (char*)d_ws;
    const size_t MB = 1024u * 1024u;

    // diagnostic hedge: always produce residual even if ws too small
    copy4_k<<<(int)(SZ_ROWDM / 4 / 256), 256, 0, stream>>>(
        (const float4*)x, (float4*)res_p, (int)(SZ_ROWDM / 4));

    if (ws_size < 116 * MB) return;   // lean plan needs ~114.1 MB

    float* xn    = (float*)(base);
    float* h_red = xn;
    bf16*  bufX  = (bf16*)(base + 16 * MB);
    bf16*  bufZ  = (bf16*)(base + 64 * MB);
    float* xdbl  = (float*)(base + 112 * MB);
    float* gqm   = (float*)(base + 114 * MB);
    bf16*  proj  = bufX;
    float* xqw   = (float*)(base + 42 * MB);
    float* gated = (float*)(base + 64 * MB);
    float* chid  = (float*)(base + 80 * MB);
    float* zlong = (float*)(base + 96 * MB);
    float* zttt  = (float*)(base + 16 * MB);
    float* gq    = (float*)(base + 32 * MB);
    float* gk    = (float*)(base + 48 * MB);

    // 2. rmsnorm -> xn
    rmsnorm_k<<<NROWS, 256, 0, stream>>>(x, norm_w, xn);

    // 3. in_proj: xx (bufX bf16), z (bufZ bf16)
    {
        dim3 g(NROWS / 64, DI / 64);
        gemm_nt<float, bf16, 0><<<g, 256, 0, stream>>>(xn, DM, in_proj_w, DM, nullptr,
                                                       bufX, DI, DI, DM);
        gemm_nt<float, bf16, 0><<<g, 256, 0, stream>>>(xn, DM, in_proj_w + (size_t)DI * DM, DM,
                                                       nullptr, bufZ, DI, DI, DM);
    }

    // 4. conv + silu in-place on bufX
    conv_silu_inplace_k<<<(BATCH * DI) / 256, 256, 0, stream>>>(bufX, conv_w, conv_b);

    // 5. x_dbl = xb @ x_proj_w.T  (N=48, K=3072)
    {
        dim3 g(NROWS / 64, 1);
        gemm_nt<bf16, float, 0><<<g, 256, 0, stream>>>(bufX, DI, x_proj_w, DI, nullptr,
                                                       xdbl, 48, 48, DI);
    }

    // 6+7. longhorn scan (fused dt matvec), y written in-place over bufX
    longhorn_k<<<(BATCH * DI) / 256, 256, 0, stream>>>(bufX, bufZ, xdbl, dt_head_w,
                                                       dt_head_b, Dvec);

    // 8. h_red = y @ reduce_w.T -> W0
    {
        dim3 g(NROWS / 64, DM / 64);
        gemm_nt<bf16, float, 0><<<g, 256, 0, stream>>>(bufX, DI, reduce_w, DI, nullptr,
                                                       h_red, DM, DM, DI);
    }

    // 9. proj = h_red @ qkv_w.T + qkv_b -> bf16 (over dead y region)
    {
        dim3 g(NROWS / 64, (PROJW + 63) / 64);
        gemm_nt<float, bf16, 1><<<g, 256, 0, stream>>>(h_red, DM, qkv_w, DM, qkv_b,
                                                       proj, PROJW, PROJW, DM);
    }

    // 10. TTT scan -> xqw f32
    ttt_k<<<BATCH * 8, 64, 0, stream>>>(proj, ttt_lr_bias, W1, b1, token_idx, token_bias,
                                        ttt_ln_w, ttt_ln_b, xqw);

    // 11. post-norm + gelu gate -> gated (over dead z region)
    gated_k<<<NROWS, 256, 0, stream>>>(xqw, proj, post_norm_w, post_norm_b, gated);

    // 12. c_hidden = gated @ wo_w.T + wo_b
    {
        dim3 g(NROWS / 64, DM / 64);
        gemm_nt<float, float, 1><<<g, 256, 0, stream>>>(gated, DM, wo_w, DM, wo_b,
                                                        chid, DM, DM, DM);
        // 13-16. four 512x512 projections
        gemm_nt<float, float, 0><<<g, 256, 0, stream>>>(h_red, DM, q_net_w, DM, nullptr,
                                                        zlong, DM, DM, DM);
        gemm_nt<float, float, 0><<<g, 256, 0, stream>>>(chid, DM, q_net_w, DM, nullptr,
                                                        zttt, DM, DM, DM);
        gemm_nt<float, float, 0><<<g, 256, 0, stream>>>(h_red, DM, gain_q_w, DM, nullptr,
                                                        gq, DM, DM, DM);
        gemm_nt<float, float, 0><<<g, 256, 0, stream>>>(h_red, DM, gain_k_w, DM, nullptr,
                                                        gk, DM, DM, DM);
    }

    // 17. gq mean over L
    mean_k<<<8, 256, 0, stream>>>(gq, gqm);

    // 18. gain + final mix
    final_k<<<NROWS, 64, 0, stream>>>(zlong, zttt, gk, gqm, alpha, beta, out_p, gain_p);
}

// Round 3
// 5481.730 us; speedup vs baseline: 1.2523x; 1.2523x over previous
//
#include <hip/hip_runtime.h>
#include <hip/hip_bf16.h>
#include <cstdint>
#include <cstddef>

#define L_SEQ 2048
#define BATCH 4
#define DM    512
#define DI    3072
#define NROWS (BATCH * L_SEQ)   // 8192
#define PROJW 1544              // 3*512 + 8

using bf16 = __hip_bfloat16;

typedef __attribute__((ext_vector_type(8))) short short8v;
typedef __attribute__((ext_vector_type(4))) float f32x4;

// ---------------------------------------------------------------- utilities

__device__ __forceinline__ float sigmoidf_(float x) { return 1.f / (1.f + __expf(-x)); }
__device__ __forceinline__ float us2f(unsigned int u) {
    union { unsigned int i; float f; } c; c.i = u << 16; return c.f;
}
__device__ __forceinline__ bf16  f2b(float f) { return __float2bfloat16(f); }
__device__ __forceinline__ float b2f(bf16 v)  { return __bfloat162float(v); }
__device__ __forceinline__ void st1(float* p, float v) { *p = v; }
__device__ __forceinline__ void st1(bf16* p, float v)  { *p = f2b(v); }

// ---------------------------------------------------------------- residual copy
__global__ __launch_bounds__(256) void copy4_k(const float4* __restrict__ in,
                                               float4* __restrict__ out, int n) {
    int i = blockIdx.x * 256 + threadIdx.x;
    if (i < n) out[i] = in[i];
}

// ---------------------------------------------------------------- f32 -> bf16 weight convert
__global__ __launch_bounds__(256) void cvt_k(const float* __restrict__ in,
                                             bf16* __restrict__ out, int n4) {
    int i = blockIdx.x * 256 + threadIdx.x;
    if (i >= n4) return;
    float4 v = ((const float4*)in)[i];
    out[4 * i + 0] = f2b(v.x);
    out[4 * i + 1] = f2b(v.y);
    out[4 * i + 2] = f2b(v.z);
    out[4 * i + 3] = f2b(v.w);
}

// ---------------------------------------------------------------- rmsnorm (row=512) -> bf16
__global__ __launch_bounds__(256) void rmsnorm_k(const float* __restrict__ x,
                                                 const float* __restrict__ w,
                                                 bf16* __restrict__ xn) {
    int r = blockIdx.x, tid = threadIdx.x;
    const float* row = x + (size_t)r * DM;
    float v0 = row[tid], v1 = row[tid + 256];
    float q = v0 * v0 + v1 * v1;
#pragma unroll
    for (int off = 32; off; off >>= 1) q += __shfl_xor(q, off);
    __shared__ float sm[4];
    if ((tid & 63) == 0) sm[tid >> 6] = q;
    __syncthreads();
    q = sm[0] + sm[1] + sm[2] + sm[3];
    float scale = rsqrtf(q * (1.f / 512.f) + 1e-5f);
    bf16* orow = xn + (size_t)r * DM;
    orow[tid]       = f2b(v0 * scale * w[tid]);
    orow[tid + 256] = f2b(v1 * scale * w[tid + 256]);
}

// ---------------------------------------------------------------- bf16 MFMA GEMM
// C[m,n] = sum_k A[m*lda+k] * W[n*ldw+k] (+ bias[n])
// 128x128 tile, BK=32, 256 threads (4 waves, 2x2), 16x16x32 MFMA.
// M % 128 == 0, K % 32 == 0, N arbitrary (B-row staging clamped, C-write guarded).
template <int BIAS, typename TC>
__global__ __launch_bounds__(256) void gemm_mfma(const bf16* __restrict__ A, int lda,
                                                 const bf16* __restrict__ Wb, int ldw,
                                                 const float* __restrict__ bias,
                                                 TC* __restrict__ C, int ldc,
                                                 int N, int K) {
    // padded rows: 48 bf16 (96 B) per 32-element row -> conflict-spread b128 reads
    __shared__ __align__(16) bf16 As[128 * 48];
    __shared__ __align__(16) bf16 Ws[128 * 48];
    const int tid = threadIdx.x;
    const int lane = tid & 63;
    const int widx = tid >> 6;
    const int bm = blockIdx.x * 128;
    const int bn = blockIdx.y * 128;
    const int wr = (widx >> 1) * 64;
    const int wc = (widx & 1) * 64;

    f32x4 acc[4][4];
#pragma unroll
    for (int i = 0; i < 4; ++i)
#pragma unroll
        for (int j = 0; j < 4; ++j) acc[i][j] = (f32x4){0.f, 0.f, 0.f, 0.f};

    const int r0 = tid >> 2;      // staging row 0..63 (and +64)
    const int c0 = tid & 3;       // 16B chunk within 64B row
    const int frow = lane & 15;
    const int fk = (lane >> 4) * 8;

    int n0 = bn + r0;       if (n0 > N - 1) n0 = N - 1;
    int n1 = bn + r0 + 64;  if (n1 > N - 1) n1 = N - 1;
    const bf16* pa0 = A + (size_t)(bm + r0) * lda + c0 * 8;
    const bf16* pa1 = A + (size_t)(bm + r0 + 64) * lda + c0 * 8;
    const bf16* pb0 = Wb + (size_t)n0 * ldw + c0 * 8;
    const bf16* pb1 = Wb + (size_t)n1 * ldw + c0 * 8;

    for (int k0 = 0; k0 < K; k0 += 32) {
        short8v a0 = *(const short8v*)(pa0 + k0);
        short8v a1 = *(const short8v*)(pa1 + k0);
        short8v b0 = *(const short8v*)(pb0 + k0);
        short8v b1 = *(const short8v*)(pb1 + k0);
        __syncthreads();    // previous iteration's fragment reads complete
        *(short8v*)&As[r0 * 48 + c0 * 8] = a0;
        *(short8v*)&As[(r0 + 64) * 48 + c0 * 8] = a1;
        *(short8v*)&Ws[r0 * 48 + c0 * 8] = b0;
        *(short8v*)&Ws[(r0 + 64) * 48 + c0 * 8] = b1;
        __syncthreads();
        short8v af[4], bg[4];
#pragma unroll
        for (int mi = 0; mi < 4; ++mi)
            af[mi] = *(const short8v*)&As[(wr + mi * 16 + frow) * 48 + fk];
#pragma unroll
        for (int ni = 0; ni < 4; ++ni)
            bg[ni] = *(const short8v*)&Ws[(wc + ni * 16 + frow) * 48 + fk];
#pragma unroll
        for (int mi = 0; mi < 4; ++mi)
#pragma unroll
            for (int ni = 0; ni < 4; ++ni)
                acc[mi][ni] = __builtin_amdgcn_mfma_f32_16x16x32_bf16(
                    af[mi], bg[ni], acc[mi][ni], 0, 0, 0);
    }

#pragma unroll
    for (int ni = 0; ni < 4; ++ni) {
        int col = bn + wc + ni * 16 + (lane & 15);
        if (col < N) {
            float bz = BIAS ? bias[col] : 0.f;
#pragma unroll
            for (int mi = 0; mi < 4; ++mi) {
                int rbase = bm + wr + mi * 16 + (lane >> 4) * 4;
#pragma unroll
                for (int r = 0; r < 4; ++r) {
                    float v = acc[mi][ni][r] + bz;
                    st1(&C[(size_t)(rbase + r) * ldc + col], v);
                }
            }
        }
    }
}

// ---------------------------------------------------------------- causal depthwise conv3 + silu (in-place, bf16)
__global__ __launch_bounds__(256) void conv_silu_inplace_k(bf16* __restrict__ x,
                                                           const float* __restrict__ cw,
                                                           const float* __restrict__ cb) {
    int tid = blockIdx.x * 256 + threadIdx.x;
    if (tid >= BATCH * DI) return;
    int b = tid / DI, d = tid % DI;
    float w0 = cw[d * 3], w1 = cw[d * 3 + 1], w2 = cw[d * 3 + 2], bias = cb[d];
    size_t base = (size_t)b * L_SEQ * DI + d;
    float xm2 = 0.f, xm1 = 0.f;
    float cur = b2f(x[base]);
    for (int l = 0; l < L_SEQ; ++l) {
        float nxt = (l + 1 < L_SEQ) ? b2f(x[base + (size_t)(l + 1) * DI]) : 0.f;
        float acc = bias + w0 * xm2 + w1 * xm1 + w2 * cur;
        float o = acc * sigmoidf_(acc);
        x[base + (size_t)l * DI] = f2b(o);
        xm2 = xm1; xm1 = cur; cur = nxt;
    }
}

// ---------------------------------------------------------------- longhorn selective scan (fused dt matvec)
__global__ __launch_bounds__(256) void longhorn_k(bf16* __restrict__ xb_y,
                                                  const bf16* __restrict__ z,
                                                  const float* __restrict__ xdbl,
                                                  const float* __restrict__ dtw,
                                                  const float* __restrict__ dtb_v,
                                                  const float* __restrict__ Dv) {
    int tid = blockIdx.x * 256 + threadIdx.x;   // 0..12287
    int b = tid / DI;
    int d = tid % DI;
    float w32[32];
#pragma unroll
    for (int i = 0; i < 32; ++i) w32[i] = dtw[d * 32 + i];
    float s[8] = {0.f, 0.f, 0.f, 0.f, 0.f, 0.f, 0.f, 0.f};
    float dtb = dtb_v[d], Dd = Dv[d];
    size_t rbase = (size_t)b * L_SEQ * DI + d;
    const float* xdb = xdbl + (size_t)b * L_SEQ * 48;

    float xv = b2f(xb_y[rbase]);
    float zv = b2f(z[rbase]);

    for (int t = 0; t < L_SEQ; ++t) {
        float x_c = xv, z_c = zv;
        if (t + 1 < L_SEQ) {
            size_t nidx = rbase + (size_t)(t + 1) * DI;
            xv = b2f(xb_y[nidx]);
            zv = b2f(z[nidx]);
        }
        const float* row = xdb + (size_t)t * 48;
        float dt_c = 0.f;
#pragma unroll
        for (int i = 0; i < 32; i += 4) {
            float4 r4 = *(const float4*)(row + i);
            dt_c = fmaf(r4.x, w32[i + 0], dt_c);
            dt_c = fmaf(r4.y, w32[i + 1], dt_c);
            dt_c = fmaf(r4.z, w32[i + 2], dt_c);
            dt_c = fmaf(r4.w, w32[i + 3], dt_c);
        }
        float kq[16];
#pragma unroll
        for (int i = 0; i < 16; i += 4) *(float4*)&kq[i] = *(const float4*)(row + 32 + i);

        float sig = sigmoidf_(dt_c + dtb);
        float ksq = 0.f;
#pragma unroll
        for (int n = 0; n < 8; ++n) ksq = fmaf(kq[n], kq[n], ksq);
        float dts = sig / (1.f + sig * ksq);
        float y = 0.f;
#pragma unroll
        for (int n = 0; n < 8; ++n) {
            float dB = dts * kq[n];
            s[n] = s[n] * (1.f - dB * kq[n]) + x_c * dB;
            y = fmaf(s[n], kq[8 + n], y);
        }
        y = fmaf(Dd, x_c, y);
        float out = y * (z_c * sigmoidf_(z_c));
        xb_y[rbase + (size_t)t * DI] = f2b(out);
    }
}

// ---------------------------------------------------------------- TTT scan (pipelined, 2 butterfly rounds)
// one wave per (b,h). lane g owns W[:,g].
// identities used (exact algebra):
//   z1_t = xk_t@W_{t-2} + b_{t-2} - eta_{t-1}*(xk_t.xk_{t-1}+1)*grad_{t-1}
//   A = Sum gxh = istd*(P1 - mu*P0) + Q0,  B = istd^2*(P2-2mu P1+mu^2 P0)+istd*(Q1-mu Q0)
//   Z1q = z1 - eta*(Sum xk^2 + 1)*grad ;  mean(Z1q) = mu (since Sum grad = 0)
__global__ __launch_bounds__(64) void ttt_k(const bf16* __restrict__ proj,
                                            const float* __restrict__ lr_bias,
                                            const float* __restrict__ W1,
                                            const float* __restrict__ b1,
                                            const float* __restrict__ tok_idx,
                                            const float* __restrict__ tok_bias,
                                            const float* __restrict__ ln_w,
                                            const float* __restrict__ ln_b,
                                            bf16* __restrict__ xqw) {
    const int lane = threadIdx.x;
    const int bh = blockIdx.x;
    const int b = bh >> 3, h = bh & 7;
    __shared__ __align__(16) float sxk[3][64];

    float W[64];
#pragma unroll
    for (int f = 0; f < 64; ++f) W[f] = W1[(size_t)(h * 64 + f) * 64 + lane];
    float bvec = b1[h * 64 + lane];
    float lw = ln_w[h * 64 + lane];
    float lb = ln_b[h * 64 + lane];
    float lrb = lr_bias[h];
    float p = lw * lw;

    float P0 = p;
#pragma unroll
    for (int off = 32; off; off >>= 1) P0 += __shfl_xor(P0, off);

    const bf16* pb = proj + (size_t)b * L_SEQ * PROJW;
    float xk_c = b2f(pb[h * 64 + lane]);
    float xv_c = b2f(pb[512 + h * 64 + lane]);
    float lr_c = b2f(pb[1536 + h]);
    const bf16* p1r = pb + PROJW;
    float xk_n = b2f(p1r[h * 64 + lane]);
    float xv_n = b2f(p1r[512 + h * 64 + lane]);
    float lr_n = b2f(p1r[1536 + h]);

    float tok_c = fmaxf(tok_idx[0] + tok_bias[0], 0.f);
    float tok_n = fmaxf(tok_idx[1] + tok_bias[1], 0.f);

    sxk[0][lane] = xk_c;
    sxk[1][lane] = 0.f;
    sxk[2][lane] = 0.f;
    __syncthreads();

    float m1;
    {
        const float4* k4 = (const float4*)sxk[0];
        float a0 = 0.f, a1 = 0.f, a2 = 0.f, a3 = 0.f;
#pragma unroll
        for (int fb = 0; fb < 16; ++fb) {
            float4 kv = k4[fb];
            a0 = fmaf(kv.x, W[4 * fb + 0], a0);
            a1 = fmaf(kv.y, W[4 * fb + 1], a1);
            a2 = fmaf(kv.z, W[4 * fb + 2], a2);
            a3 = fmaf(kv.w, W[4 * fb + 3], a3);
        }
        m1 = (a0 + a1) + (a2 + a3) + bvec;
    }

    float corr = 0.f, c1p = 0.f;
    int bufp = 2, bufc = 0;

    bf16* xq = xqw + ((size_t)b * L_SEQ) * DM + h * 64 + lane;

    for (int t = 0; t < L_SEQ; ++t) {
        int bufn = 3 - bufp - bufc;
        sxk[bufn][lane] = xk_n;

        // corrected z1 for current token
        float z1 = m1 - corr;

        // per-lane pre-reduce values
        float q = (lb - xv_c + xk_c) * lw;
        float s1 = z1, s2 = z1 * z1;
        float pz1 = p * z1, pz2 = p * s2;
        float q0 = q, q1 = q * z1;
        float k2 = xk_c * xk_c, d13 = xk_c * xk_n;
#pragma unroll
        for (int off = 32; off; off >>= 1) {
            s1 += __shfl_xor(s1, off);
            s2 += __shfl_xor(s2, off);
            pz1 += __shfl_xor(pz1, off);
            pz2 += __shfl_xor(pz2, off);
            q0 += __shfl_xor(q0, off);
            q1 += __shfl_xor(q1, off);
            k2 += __shfl_xor(k2, off);
            d13 += __shfl_xor(d13, off);
        }

        // W/b update (token t-1) fused with matvec for token t+1 (overlaps butterflies)
        float m1n;
        {
            const float4* kp4 = (const float4*)sxk[bufp];
            const float4* kn4 = (const float4*)sxk[bufn];
            float a0 = 0.f, a1 = 0.f, a2 = 0.f, a3 = 0.f;
#pragma unroll
            for (int fb = 0; fb < 16; ++fb) {
                float4 kp = kp4[fb];
                float4 kn = kn4[fb];
                float w0 = fmaf(-c1p, kp.x, W[4 * fb + 0]); W[4 * fb + 0] = w0; a0 = fmaf(kn.x, w0, a0);
                float w1 = fmaf(-c1p, kp.y, W[4 * fb + 1]); W[4 * fb + 1] = w1; a1 = fmaf(kn.y, w1, a1);
                float w2 = fmaf(-c1p, kp.z, W[4 * fb + 2]); W[4 * fb + 2] = w2; a2 = fmaf(kn.z, w2, a2);
                float w3 = fmaf(-c1p, kp.w, W[4 * fb + 3]); W[4 * fb + 3] = w3; a3 = fmaf(kn.w, w3, a3);
            }
            bvec -= c1p;
            m1n = (a0 + a1) + (a2 + a3) + bvec;
        }

        // scalar LN-backward algebra from round-1 sums
        float mu = s1 * 0.015625f;
        float var = fmaf(s2, 0.015625f, -mu * mu);
        float istd = rsqrtf(var + 1e-6f);
        float A_ = fmaf(istd, pz1 - mu * P0, q0);
        float Bv = istd * istd * (pz2 - 2.f * mu * pz1 + mu * mu * P0) + istd * (q1 - mu * q0);
        float xh = (z1 - mu) * istd;
        float gxh = fmaf(p, xh, q);
        float grad = (64.f * gxh - A_ - xh * Bv) * (istd * 0.015625f);
        float eta = tok_c * sigmoidf_(lr_c + lrb);
        float z1q = z1 - eta * (k2 + 1.f) * grad;

        // round 2: variance of z1q around mu
        float dq = z1q - mu;
        float sq = dq * dq;
#pragma unroll
        for (int off = 32; off; off >>= 1) sq += __shfl_xor(sq, off);
        float istd2 = rsqrtf(fmaf(sq, 0.015625f, 1e-6f));
        float outv = fmaf(lw, dq * istd2, xk_c + lb);
        xq[(size_t)t * DM] = f2b(outv);

        // carries
        float eg = eta * grad;
        corr = eg * (d13 + 1.f);
        c1p = eg;
        m1 = m1n;
        bufp = bufc; bufc = bufn;

        // prefetch token t+2
        xk_c = xk_n; xv_c = xv_n; lr_c = lr_n; tok_c = tok_n;
        int tn = t + 2; if (tn > L_SEQ - 1) tn = L_SEQ - 1;
        const bf16* pr = pb + (size_t)tn * PROJW;
        xk_n = b2f(pr[h * 64 + lane]);
        xv_n = b2f(pr[512 + h * 64 + lane]);
        lr_n = b2f(pr[1536 + h]);
        tok_n = fmaxf(tok_idx[tn] + tok_bias[tn], 0.f);
    }
}

// ---------------------------------------------------------------- post-norm + gelu gate
__global__ __launch_bounds__(256) void gated_k(const bf16* __restrict__ xqw,
                                               const bf16* __restrict__ proj,
                                               const float* __restrict__ pnw,
                                               const float* __restrict__ pnb,
                                               bf16* __restrict__ gated) {
    int r = blockIdx.x, tid = threadIdx.x;
    const bf16* row = xqw + (size_t)r * DM;
    float v0 = b2f(row[tid]), v1 = b2f(row[tid + 256]);
    float s = v0 + v1, q = v0 * v0 + v1 * v1;
#pragma unroll
    for (int off = 32; off; off >>= 1) {
        s += __shfl_xor(s, off);
        q += __shfl_xor(q, off);
    }
    __shared__ float sm[8];
    if ((tid & 63) == 0) { sm[tid >> 6] = s; sm[4 + (tid >> 6)] = q; }
    __syncthreads();
    s = sm[0] + sm[1] + sm[2] + sm[3];
    q = sm[4] + sm[5] + sm[6] + sm[7];
    float mu = s * (1.f / 512.f);
    float var = q * (1.f / 512.f) - mu * mu;
    float istd = rsqrtf(var + 1e-5f);
    const bf16* grow = proj + (size_t)r * PROJW + 1024;
    bf16* orow = gated + (size_t)r * DM;
#pragma unroll
    for (int e = 0; e < 2; ++e) {
        int c = tid + e * 256;
        float xv = (e == 0) ? v0 : v1;
        float nv = (xv - mu) * istd * pnw[c] + pnb[c];
        float g = b2f(grow[c]);
        float gg = 0.5f * g * (1.f + tanhf(0.7978845608028654f * (g + 0.044715f * g * g * g)));
        orow[c] = f2b(gg * nv);
    }
}

// ---------------------------------------------------------------- gq mean over L
__global__ __launch_bounds__(256) void mean_k(const float* __restrict__ gq,
                                              float* __restrict__ gqm) {
    int t = blockIdx.x * 256 + threadIdx.x;  // 0..2047
    int b = t >> 9, d = t & 511;
    const float* p = gq + (size_t)b * L_SEQ * DM + d;
    float acc = 0.f;
    for (int l = 0; l < L_SEQ; ++l) acc += p[(size_t)l * DM];
    gqm[t] = acc * (1.f / (float)L_SEQ);
}

// ---------------------------------------------------------------- gain + final mix
__global__ __launch_bounds__(64) void final_k(const float* __restrict__ zl,
                                              const float* __restrict__ zt,
                                              const float* __restrict__ gk,
                                              const float* __restrict__ gqm,
                                              const float* __restrict__ alpha,
                                              const float* __restrict__ beta,
                                              float* __restrict__ out,
                                              float* __restrict__ gain_out) {
    int r = blockIdx.x;          // 0..8191
    int lane = threadIdx.x;
    int b = r >> 11;
    const float* gkr = gk + (size_t)r * DM;
    const float* gmb = gqm + b * DM;
    float acc = 0.f;
#pragma unroll
    for (int i = 0; i < 8; ++i) acc = fmaf(gmb[lane + 64 * i], gkr[lane + 64 * i], acc);
#pragma unroll
    for (int off = 32; off; off >>= 1) acc += __shfl_xor(acc, off);
    float score = acc * 0.04419417382415922f;   // 1/sqrt(512)
    float g = sigmoidf_(alpha[0] * score + beta[0]);
    g = fminf(g, 0.55f);
    if (lane == 0) gain_out[r] = g;
    const float* zlr = zl + (size_t)r * DM;
    const float* ztr = zt + (size_t)r * DM;
    float* orow = out + (size_t)r * DM;
#pragma unroll
    for (int i = 0; i < 8; ++i) {
        int c = lane + 64 * i;
        float a = zlr[c];
        orow[c] = a + g * (ztr[c] - a);
    }
}

// ---------------------------------------------------------------- host launcher

extern "C" void kernel_launch(void* const* d_in, const int* in_sizes, int n_in,
                              void* d_out, int out_size, void* d_ws, size_t ws_size,
                              hipStream_t stream) {
    const float* x           = (const float*)d_in[0];
    const float* norm_w      = (const float*)d_in[1];
    const float* in_proj_w   = (const float*)d_in[2];
    const float* conv_w      = (const float*)d_in[3];
    const float* conv_b      = (const float*)d_in[4];
    const float* x_proj_w    = (const float*)d_in[5];
    const float* dt_head_w   = (const float*)d_in[6];
    const float* dt_head_b   = (const float*)d_in[7];
    const float* Dvec        = (const float*)d_in[8];
    const float* reduce_w    = (const float*)d_in[9];
    const float* q_net_w     = (const float*)d_in[10];
    const float* gain_q_w    = (const float*)d_in[11];
    const float* gain_k_w    = (const float*)d_in[12];
    const float* alpha       = (const float*)d_in[13];
    const float* beta        = (const float*)d_in[14];
    const float* qkv_w       = (const float*)d_in[15];
    const float* qkv_b       = (const float*)d_in[16];
    const float* ttt_lr_bias = (const float*)d_in[17];
    const float* W1          = (const float*)d_in[18];
    const float* b1          = (const float*)d_in[19];
    const float* token_idx   = (const float*)d_in[20];
    const float* token_bias  = (const float*)d_in[21];
    const float* ttt_ln_w    = (const float*)d_in[22];
    const float* ttt_ln_b    = (const float*)d_in[23];
    const float* post_norm_w = (const float*)d_in[24];
    const float* post_norm_b = (const float*)d_in[25];
    const float* wo_w        = (const float*)d_in[26];
    const float* wo_b        = (const float*)d_in[27];

    const size_t SZ_ROWDM = (size_t)NROWS * DM;   // 4,194,304 elements
    const size_t MB = 1024u * 1024u;
    char* base = (char*)d_ws;

    float* out_p  = (float*)d_out;
    float* res_p  = out_p + SZ_ROWDM;
    float* gain_p = out_p + 2 * SZ_ROWDM;

    copy4_k<<<(int)(SZ_ROWDM / 4 / 256), 256, 0, stream>>>(
        (const float4*)x, (float4*)res_p, (int)(SZ_ROWDM / 4));

    if (ws_size < 116 * MB) return;

    // ---- workspace layout (byte offsets, MB units) -- peak ~113.6 MB
    bf16*  ws0   = (bf16*)base;                     // [0, 6.5)  weight scratch (bf16)
    bf16*  xn    = (bf16*)(base + 7 * MB);          // [7, 15)   xn -> later h_red
    bf16*  h_red = xn;
    bf16*  bufX  = (bf16*)(base + 16 * MB);         // [16, 64)  xx/xb/y -> proj
    bf16*  bufZ  = (bf16*)(base + 64 * MB);         // [64, 112) z -> xqw/gk
    float* xdbl  = (float*)(base + 112 * MB);       // [112, 113.5)
    float* gqm   = (float*)(base + 113 * MB + 512 * 1024);
    bf16*  proj  = bufX;                            // [16, 41.3)
    bf16*  xqw   = bufZ;                            // [64, 72)
    bf16*  gated = (bf16*)(base + 72 * MB);         // [72, 80)
    bf16*  chid  = (bf16*)(base + 80 * MB);         // [80, 88)
    float* zlong = (float*)(base + 88 * MB);        // [88, 104)
    float* zttt  = (float*)(base + 42 * MB);        // [42, 58)
    float* gq    = (float*)(base + 16 * MB);        // [16, 32) (proj dead by then)
    float* gk    = (float*)(base + 64 * MB);        // [64, 80) (xqw+gated dead by then)

    // rmsnorm -> xn bf16
    rmsnorm_k<<<NROWS, 256, 0, stream>>>(x, norm_w, xn);

    // in_proj (both halves)
    cvt_k<<<(2 * DI * DM / 4 + 255) / 256, 256, 0, stream>>>(in_proj_w, ws0, 2 * DI * DM / 4);
    {
        dim3 g(NROWS / 128, DI / 128);
        gemm_mfma<0, bf16><<<g, 256, 0, stream>>>(xn, DM, ws0, DM, nullptr, bufX, DI, DI, DM);
        gemm_mfma<0, bf16><<<g, 256, 0, stream>>>(xn, DM, ws0 + (size_t)DI * DM, DM, nullptr, bufZ, DI, DI, DM);
    }

    conv_silu_inplace_k<<<(BATCH * DI) / 256, 256, 0, stream>>>(bufX, conv_w, conv_b);

    // x_proj -> xdbl f32
    cvt_k<<<(48 * DI / 4 + 255) / 256, 256, 0, stream>>>(x_proj_w, ws0, 48 * DI / 4);
    {
        dim3 g(NROWS / 128, 1);
        gemm_mfma<0, float><<<g, 256, 0, stream>>>(bufX, DI, ws0, DI, nullptr, xdbl, 48, 48, DI);
    }

    longhorn_k<<<(BATCH * DI) / 256, 256, 0, stream>>>(bufX, bufZ, xdbl, dt_head_w, dt_head_b, Dvec);

    // reduce -> h_red bf16
    cvt_k<<<(DM * DI / 4 + 255) / 256, 256, 0, stream>>>(reduce_w, ws0, DM * DI / 4);
    {
        dim3 g(NROWS / 128, DM / 128);
        gemm_mfma<0, bf16><<<g, 256, 0, stream>>>(bufX, DI, ws0, DI, nullptr, h_red, DM, DM, DI);
    }

    // qkv -> proj bf16
    cvt_k<<<(PROJW * DM / 4 + 255) / 256, 256, 0, stream>>>(qkv_w, ws0, PROJW * DM / 4);
    {
        dim3 g(NROWS / 128, (PROJW + 127) / 128);
        gemm_mfma<1, bf16><<<g, 256, 0, stream>>>(h_red, DM, ws0, DM, qkv_b, proj, PROJW, PROJW, DM);
    }

    ttt_k<<<BATCH * 8, 64, 0, stream>>>(proj, ttt_lr_bias, W1, b1, token_idx, token_bias,
                                        ttt_ln_w, ttt_ln_b, xqw);

    gated_k<<<NROWS, 256, 0, stream>>>(xqw, proj, post_norm_w, post_norm_b, gated);

    // wo -> chid bf16
    cvt_k<<<(DM * DM / 4 + 255) / 256, 256, 0, stream>>>(wo_w, ws0, DM * DM / 4);
    {
        dim3 g(NROWS / 128, DM / 128);
        gemm_mfma<1, bf16><<<g, 256, 0, stream>>>(gated, DM, ws0, DM, wo_b, chid, DM, DM, DM);
    }

    // q_net: zlong (from h_red) and zttt (from chid)
    cvt_k<<<(DM * DM / 4 + 255) / 256, 256, 0, stream>>>(q_net_w, ws0, DM * DM / 4);
    {
        dim3 g(NROWS / 128, DM / 128);
        gemm_mfma<0, float><<<g, 256, 0, stream>>>(h_red, DM, ws0, DM, nullptr, zlong, DM, DM, DM);
        gemm_mfma<0, float><<<g, 256, 0, stream>>>(chid, DM, ws0, DM, nullptr, zttt, DM, DM, DM);
    }

    // gain_q -> gq
    cvt_k<<<(DM * DM / 4 + 255) / 256, 256, 0, stream>>>(gain_q_w, ws0, DM * DM / 4);
    {
        dim3 g(NROWS / 128, DM / 128);
        gemm_mfma<0, float><<<g, 256, 0, stream>>>(h_red, DM, ws0, DM, nullptr, gq, DM, DM, DM);
    }
    // gain_k -> gk
    cvt_k<<<(DM * DM / 4 + 255) / 256, 256, 0, stream>>>(gain_k_w, ws0, DM * DM / 4);
    {
        dim3 g(NROWS / 128, DM / 128);
        gemm_mfma<0, float><<<g, 256, 0, stream>>>(h_red, DM, ws0, DM, nullptr, gk, DM, DM, DM);
    }

    mean_k<<<8, 256, 0, stream>>>(gq, gqm);
    final_k<<<NROWS, 64, 0, stream>>>(zlong, zttt, gk, gqm, alpha, beta, out_p, gain_p);
}

// Round 4
// 5337.948 us; speedup vs baseline: 1.2860x; 1.0269x over previous
//
#include <hip/hip_runtime.h>
#include <hip/hip_bf16.h>
#include <cstdint>
#include <cstddef>

#define L_SEQ 2048
#define BATCH 4
#define DM    512
#define DI    3072
#define NROWS (BATCH * L_SEQ)   // 8192
#define PROJW 1544              // 3*512 + 8
#define CTILE 16
#define BDI   (BATCH * DI)      // 12288

using bf16 = __hip_bfloat16;

typedef __attribute__((ext_vector_type(8))) short short8v;
typedef __attribute__((ext_vector_type(4))) float f32x4;

// ---------------------------------------------------------------- utilities

__device__ __forceinline__ float sigmoidf_(float x) { return 1.f / (1.f + __expf(-x)); }
__device__ __forceinline__ float us2f(unsigned int u) {
    union { unsigned int i; float f; } c; c.i = u << 16; return c.f;
}
__device__ __forceinline__ bf16  f2b(float f) { return __float2bfloat16(f); }
__device__ __forceinline__ float b2f(bf16 v)  { return __bfloat162float(v); }
__device__ __forceinline__ void st1(float* p, float v) { *p = v; }
__device__ __forceinline__ void st1(bf16* p, float v)  { *p = f2b(v); }

// DPP-based wave64 sum -> uniform value (rocPRIM pattern: shr 1,2,4,8 + bcast15/31 + readlane63)
template <int CTRL>
__device__ __forceinline__ float dppadd_(float x) {
    int s = __builtin_amdgcn_update_dpp(0, __builtin_bit_cast(int, x), CTRL, 0xF, 0xF, true);
    return x + __builtin_bit_cast(float, s);
}
__device__ __forceinline__ float wave_sum_u(float x) {
    x = dppadd_<0x111>(x);   // row_shr:1
    x = dppadd_<0x112>(x);   // row_shr:2
    x = dppadd_<0x114>(x);   // row_shr:4
    x = dppadd_<0x118>(x);   // row_shr:8
    x = dppadd_<0x142>(x);   // row_bcast:15
    x = dppadd_<0x143>(x);   // row_bcast:31  -> total in lane 63
    return __builtin_bit_cast(float,
        __builtin_amdgcn_readlane(__builtin_bit_cast(int, x), 63));
}

// ---------------------------------------------------------------- residual copy
__global__ __launch_bounds__(256) void copy4_k(const float4* __restrict__ in,
                                               float4* __restrict__ out, int n) {
    int i = blockIdx.x * 256 + threadIdx.x;
    if (i < n) out[i] = in[i];
}

// ---------------------------------------------------------------- f32 -> bf16 weight convert
__global__ __launch_bounds__(256) void cvt_k(const float* __restrict__ in,
                                             bf16* __restrict__ out, int n4) {
    int i = blockIdx.x * 256 + threadIdx.x;
    if (i >= n4) return;
    float4 v = ((const float4*)in)[i];
    out[4 * i + 0] = f2b(v.x);
    out[4 * i + 1] = f2b(v.y);
    out[4 * i + 2] = f2b(v.z);
    out[4 * i + 3] = f2b(v.w);
}

// ---------------------------------------------------------------- rmsnorm (row=512) -> bf16
__global__ __launch_bounds__(256) void rmsnorm_k(const float* __restrict__ x,
                                                 const float* __restrict__ w,
                                                 bf16* __restrict__ xn) {
    int r = blockIdx.x, tid = threadIdx.x;
    const float* row = x + (size_t)r * DM;
    float v0 = row[tid], v1 = row[tid + 256];
    float q = v0 * v0 + v1 * v1;
#pragma unroll
    for (int off = 32; off; off >>= 1) q += __shfl_xor(q, off);
    __shared__ float sm[4];
    if ((tid & 63) == 0) sm[tid >> 6] = q;
    __syncthreads();
    q = sm[0] + sm[1] + sm[2] + sm[3];
    float scale = rsqrtf(q * (1.f / 512.f) + 1e-5f);
    bf16* orow = xn + (size_t)r * DM;
    orow[tid]       = f2b(v0 * scale * w[tid]);
    orow[tid + 256] = f2b(v1 * scale * w[tid + 256]);
}

// ---------------------------------------------------------------- bf16 MFMA GEMM (validated R3)
template <int BIAS, typename TC>
__global__ __launch_bounds__(256) void gemm_mfma(const bf16* __restrict__ A, int lda,
                                                 const bf16* __restrict__ Wb, int ldw,
                                                 const float* __restrict__ bias,
                                                 TC* __restrict__ C, int ldc,
                                                 int N, int K) {
    __shared__ __align__(16) bf16 As[128 * 48];
    __shared__ __align__(16) bf16 Ws[128 * 48];
    const int tid = threadIdx.x;
    const int lane = tid & 63;
    const int widx = tid >> 6;
    const int bm = blockIdx.x * 128;
    const int bn = blockIdx.y * 128;
    const int wr = (widx >> 1) * 64;
    const int wc = (widx & 1) * 64;

    f32x4 acc[4][4];
#pragma unroll
    for (int i = 0; i < 4; ++i)
#pragma unroll
        for (int j = 0; j < 4; ++j) acc[i][j] = (f32x4){0.f, 0.f, 0.f, 0.f};

    const int r0 = tid >> 2;
    const int c0 = tid & 3;
    const int frow = lane & 15;
    const int fk = (lane >> 4) * 8;

    int n0 = bn + r0;       if (n0 > N - 1) n0 = N - 1;
    int n1 = bn + r0 + 64;  if (n1 > N - 1) n1 = N - 1;
    const bf16* pa0 = A + (size_t)(bm + r0) * lda + c0 * 8;
    const bf16* pa1 = A + (size_t)(bm + r0 + 64) * lda + c0 * 8;
    const bf16* pb0 = Wb + (size_t)n0 * ldw + c0 * 8;
    const bf16* pb1 = Wb + (size_t)n1 * ldw + c0 * 8;

    for (int k0 = 0; k0 < K; k0 += 32) {
        short8v a0 = *(const short8v*)(pa0 + k0);
        short8v a1 = *(const short8v*)(pa1 + k0);
        short8v b0 = *(const short8v*)(pb0 + k0);
        short8v b1 = *(const short8v*)(pb1 + k0);
        __syncthreads();
        *(short8v*)&As[r0 * 48 + c0 * 8] = a0;
        *(short8v*)&As[(r0 + 64) * 48 + c0 * 8] = a1;
        *(short8v*)&Ws[r0 * 48 + c0 * 8] = b0;
        *(short8v*)&Ws[(r0 + 64) * 48 + c0 * 8] = b1;
        __syncthreads();
        short8v af[4], bg[4];
#pragma unroll
        for (int mi = 0; mi < 4; ++mi)
            af[mi] = *(const short8v*)&As[(wr + mi * 16 + frow) * 48 + fk];
#pragma unroll
        for (int ni = 0; ni < 4; ++ni)
            bg[ni] = *(const short8v*)&Ws[(wc + ni * 16 + frow) * 48 + fk];
#pragma unroll
        for (int mi = 0; mi < 4; ++mi)
#pragma unroll
            for (int ni = 0; ni < 4; ++ni)
                acc[mi][ni] = __builtin_amdgcn_mfma_f32_16x16x32_bf16(
                    af[mi], bg[ni], acc[mi][ni], 0, 0, 0);
    }

#pragma unroll
    for (int ni = 0; ni < 4; ++ni) {
        int col = bn + wc + ni * 16 + (lane & 15);
        if (col < N) {
            float bz = BIAS ? bias[col] : 0.f;
#pragma unroll
            for (int mi = 0; mi < 4; ++mi) {
                int rbase = bm + wr + mi * 16 + (lane >> 4) * 4;
#pragma unroll
                for (int r = 0; r < 4; ++r) {
                    float v = acc[mi][ni][r] + bz;
                    st1(&C[(size_t)(rbase + r) * ldc + col], v);
                }
            }
        }
    }
}

// ---------------------------------------------------------------- conv: boundary row copy (race-free in-place tiling)
__global__ __launch_bounds__(256) void conv_boundary_k(const bf16* __restrict__ x,
                                                       bf16* __restrict__ side) {
    int idx = blockIdx.x * 256 + threadIdx.x;
    const int total = (L_SEQ / CTILE - 1) * 2 * BDI;
    if (idx >= total) return;
    int col = idx % BDI;
    int rr = idx / BDI;
    int tile = (rr >> 1) + 1;
    int r = rr & 1;
    int b = col / DI, d = col % DI;
    int l = tile * CTILE - 2 + r;
    side[idx] = x[((size_t)b * L_SEQ + l) * DI + d];
}

// ---------------------------------------------------------------- conv tile: causal depthwise conv3 + silu, in-place
__global__ __launch_bounds__(256) void conv_tile_k(bf16* __restrict__ x,
                                                   const bf16* __restrict__ side,
                                                   const float* __restrict__ cw,
                                                   const float* __restrict__ cb) {
    int idx = blockIdx.x * 256 + threadIdx.x;
    const int total = (L_SEQ / CTILE) * BDI;
    if (idx >= total) return;
    int col = idx % BDI;
    int tile = idx / BDI;
    int b = col / DI, d = col % DI;
    float w0 = cw[3 * d], w1 = cw[3 * d + 1], w2 = cw[3 * d + 2], bias = cb[d];
    size_t base = ((size_t)b * L_SEQ + tile * CTILE) * DI + d;
    float xm2, xm1;
    if (tile == 0) { xm2 = 0.f; xm1 = 0.f; }
    else {
        const bf16* sp = side + ((size_t)(tile - 1) * 2) * BDI + col;
        xm2 = b2f(sp[0]);
        xm1 = b2f(sp[BDI]);
    }
    float cur = b2f(x[base]);
#pragma unroll
    for (int i = 0; i < CTILE; ++i) {
        float nxt = (i + 1 < CTILE) ? b2f(x[base + (size_t)(i + 1) * DI]) : 0.f;
        float a = bias + w0 * xm2 + w1 * xm1 + w2 * cur;
        x[base + (size_t)i * DI] = f2b(a * sigmoidf_(a));
        xm2 = xm1; xm1 = cur; cur = nxt;
    }
}

// ---------------------------------------------------------------- longhorn selective scan (validated R3)
__global__ __launch_bounds__(256) void longhorn_k(bf16* __restrict__ xb_y,
                                                  const bf16* __restrict__ z,
                                                  const float* __restrict__ xdbl,
                                                  const float* __restrict__ dtw,
                                                  const float* __restrict__ dtb_v,
                                                  const float* __restrict__ Dv) {
    int tid = blockIdx.x * 256 + threadIdx.x;
    int b = tid / DI;
    int d = tid % DI;
    float w32[32];
#pragma unroll
    for (int i = 0; i < 32; ++i) w32[i] = dtw[d * 32 + i];
    float s[8] = {0.f, 0.f, 0.f, 0.f, 0.f, 0.f, 0.f, 0.f};
    float dtb = dtb_v[d], Dd = Dv[d];
    size_t rbase = (size_t)b * L_SEQ * DI + d;
    const float* xdb = xdbl + (size_t)b * L_SEQ * 48;

    float xv = b2f(xb_y[rbase]);
    float zv = b2f(z[rbase]);

    for (int t = 0; t < L_SEQ; ++t) {
        float x_c = xv, z_c = zv;
        if (t + 1 < L_SEQ) {
            size_t nidx = rbase + (size_t)(t + 1) * DI;
            xv = b2f(xb_y[nidx]);
            zv = b2f(z[nidx]);
        }
        const float* row = xdb + (size_t)t * 48;
        float dt_c = 0.f;
#pragma unroll
        for (int i = 0; i < 32; i += 4) {
            float4 r4 = *(const float4*)(row + i);
            dt_c = fmaf(r4.x, w32[i + 0], dt_c);
            dt_c = fmaf(r4.y, w32[i + 1], dt_c);
            dt_c = fmaf(r4.z, w32[i + 2], dt_c);
            dt_c = fmaf(r4.w, w32[i + 3], dt_c);
        }
        float kq[16];
#pragma unroll
        for (int i = 0; i < 16; i += 4) *(float4*)&kq[i] = *(const float4*)(row + 32 + i);

        float sig = sigmoidf_(dt_c + dtb);
        float ksq = 0.f;
#pragma unroll
        for (int n = 0; n < 8; ++n) ksq = fmaf(kq[n], kq[n], ksq);
        float dts = sig / (1.f + sig * ksq);
        float y = 0.f;
#pragma unroll
        for (int n = 0; n < 8; ++n) {
            float dB = dts * kq[n];
            s[n] = s[n] * (1.f - dB * kq[n]) + x_c * dB;
            y = fmaf(s[n], kq[8 + n], y);
        }
        y = fmaf(Dd, x_c, y);
        float out = y * (z_c * sigmoidf_(z_c));
        xb_y[rbase + (size_t)t * DI] = f2b(out);
    }
}

// ---------------------------------------------------------------- TTT prep: extract per-head xk (f32), eta, sum(xk^2), xk_t.xk_{t+1}
__global__ __launch_bounds__(128) void prep_ttt_k(const bf16* __restrict__ proj,
                                                  const float* __restrict__ lr_bias,
                                                  const float* __restrict__ tok_idx,
                                                  const float* __restrict__ tok_bias,
                                                  float* __restrict__ xkf,
                                                  float* __restrict__ etav,
                                                  float* __restrict__ k2s,
                                                  float* __restrict__ d13s) {
    int bh = blockIdx.x >> 4;
    int t = (blockIdx.x & 15) * 128 + threadIdx.x;
    int b = bh >> 3, h = bh & 7;
    const bf16* prow = proj + ((size_t)b * L_SEQ + t) * PROJW;
    const bf16* pk = prow + h * 64;
    float v[64];
    float k2 = 0.f;
#pragma unroll
    for (int i = 0; i < 64; i += 8) {
        short8v s = *(const short8v*)(pk + i);
#pragma unroll
        for (int j = 0; j < 8; ++j) {
            float f = us2f((unsigned short)s[j]);
            v[i + j] = f;
            k2 = fmaf(f, f, k2);
        }
    }
    float* xo = xkf + ((size_t)bh * L_SEQ + t) * 64;
#pragma unroll
    for (int i = 0; i < 64; i += 4)
        *(float4*)(xo + i) = make_float4(v[i], v[i + 1], v[i + 2], v[i + 3]);

    int tn = (t + 1 < L_SEQ) ? t + 1 : t;
    const bf16* pn = proj + ((size_t)b * L_SEQ + tn) * PROJW + h * 64;
    float d13 = 0.f;
#pragma unroll
    for (int i = 0; i < 64; i += 8) {
        short8v s = *(const short8v*)(pn + i);
#pragma unroll
        for (int j = 0; j < 8; ++j) d13 = fmaf(us2f((unsigned short)s[j]), v[i + j], d13);
    }
    float eta = sigmoidf_(b2f(prow[1536 + h]) + lr_bias[h]) *
                fmaxf(tok_idx[t] + tok_bias[t], 0.f);
    size_t o = (size_t)bh * L_SEQ + t;
    etav[o] = eta;
    k2s[o]  = k2;
    d13s[o] = d13;
}

// ---------------------------------------------------------------- TTT scan v3: DPP reductions + uniform (SMEM) matvec, no LDS
__global__ __launch_bounds__(64) void ttt_k(const bf16* __restrict__ proj,
                                            const float* __restrict__ xkf,
                                            const float* __restrict__ etav,
                                            const float* __restrict__ k2s,
                                            const float* __restrict__ d13s,
                                            const float* __restrict__ W1,
                                            const float* __restrict__ b1,
                                            const float* __restrict__ ln_w,
                                            const float* __restrict__ ln_b,
                                            bf16* __restrict__ xqw) {
    const int lane = threadIdx.x;
    const int bh = blockIdx.x;
    const int b = bh >> 3, h = bh & 7;

    float W[64];
#pragma unroll
    for (int f = 0; f < 64; ++f) W[f] = W1[(size_t)(h * 64 + f) * 64 + lane];
    float bvec = b1[h * 64 + lane];
    float lw = ln_w[h * 64 + lane];
    float lb = ln_b[h * 64 + lane];
    float p = lw * lw;
    float P0 = wave_sum_u(p);

    const float* kf  = xkf + (size_t)bh * L_SEQ * 64;
    const float* ev  = etav + (size_t)bh * L_SEQ;
    const float* k2v = k2s + (size_t)bh * L_SEQ;
    const float* dv  = d13s + (size_t)bh * L_SEQ;
    const bf16*  pb  = proj + (size_t)b * L_SEQ * PROJW;

    // m1 = xk_0 @ W + b (uniform loads)
    float m1;
    {
        float a0 = 0.f, a1 = 0.f, a2 = 0.f, a3 = 0.f;
#pragma unroll
        for (int f = 0; f < 64; f += 4) {
            float4 kv = *(const float4*)(kf + f);
            a0 = fmaf(kv.x, W[f + 0], a0);
            a1 = fmaf(kv.y, W[f + 1], a1);
            a2 = fmaf(kv.z, W[f + 2], a2);
            a3 = fmaf(kv.w, W[f + 3], a3);
        }
        m1 = (a0 + a1) + (a2 + a3) + bvec;
    }
    float corr = 0.f, c1p = 0.f;
    bf16* xq = xqw + ((size_t)b * L_SEQ) * DM + h * 64 + lane;

    float xk_c = kf[lane];
    float xv_c = b2f(pb[512 + h * 64 + lane]);

    for (int t = 0; t < L_SEQ; ++t) {
        float z1 = m1 - corr;
        float eta = ev[t], k2u = k2v[t], d13u = dv[t];

        float q = (lb - xv_c + xk_c) * lw;
        // 6 DPP reductions (VALU, ~50 cyc each, interleaved)
        float S1  = wave_sum_u(z1);
        float S2  = wave_sum_u(z1 * z1);
        float PZ1 = wave_sum_u(p * z1);
        float PZ2 = wave_sum_u(p * z1 * z1);
        float Q0  = wave_sum_u(q);
        float Q1  = wave_sum_u(q * z1);

        // fused W update (token t-1) + matvec for token t+1 (uniform s_loads)
        int tp = (t > 0) ? t - 1 : 0;
        int tn = (t + 1 < L_SEQ) ? t + 1 : t;
        const float* kp = kf + (size_t)tp * 64;
        const float* kn = kf + (size_t)tn * 64;
        float m1n;
        {
            float a0 = 0.f, a1 = 0.f, a2 = 0.f, a3 = 0.f;
#pragma unroll
            for (int f = 0; f < 64; f += 4) {
                float4 kpv = *(const float4*)(kp + f);
                float4 knv = *(const float4*)(kn + f);
                float w0 = fmaf(-c1p, kpv.x, W[f + 0]); W[f + 0] = w0; a0 = fmaf(knv.x, w0, a0);
                float w1 = fmaf(-c1p, kpv.y, W[f + 1]); W[f + 1] = w1; a1 = fmaf(knv.y, w1, a1);
                float w2 = fmaf(-c1p, kpv.z, W[f + 2]); W[f + 2] = w2; a2 = fmaf(knv.z, w2, a2);
                float w3 = fmaf(-c1p, kpv.w, W[f + 3]); W[f + 3] = w3; a3 = fmaf(knv.w, w3, a3);
            }
            bvec -= c1p;
            m1n = (a0 + a1) + (a2 + a3) + bvec;
        }

        // scalar LN-backward algebra (validated identities)
        float mu = S1 * 0.015625f;
        float var = fmaf(S2, 0.015625f, -mu * mu);
        float istd = rsqrtf(var + 1e-6f);
        float A_ = fmaf(istd, PZ1 - mu * P0, Q0);
        float Bv = istd * istd * (PZ2 - 2.f * mu * PZ1 + mu * mu * P0) + istd * (Q1 - mu * Q0);
        float xh = (z1 - mu) * istd;
        float gxh = fmaf(p, xh, q);
        float grad = (64.f * gxh - A_ - xh * Bv) * (istd * 0.015625f);
        float z1q = z1 - eta * (k2u + 1.f) * grad;

        float dq = z1q - mu;
        float SQ = wave_sum_u(dq * dq);
        float istd2 = rsqrtf(fmaf(SQ, 0.015625f, 1e-6f));
        float outv = fmaf(lw, dq * istd2, xk_c + lb);
        xq[(size_t)t * DM] = f2b(outv);

        float eg = eta * grad;
        corr = eg * (d13u + 1.f);
        c1p = eg;
        m1 = m1n;

        if (t + 1 < L_SEQ) {
            xk_c = kf[(size_t)(t + 1) * 64 + lane];
            xv_c = b2f(pb[(size_t)(t + 1) * PROJW + 512 + h * 64 + lane]);
        }
    }
}

// ---------------------------------------------------------------- post-norm + gelu gate
__global__ __launch_bounds__(256) void gated_k(const bf16* __restrict__ xqw,
                                               const bf16* __restrict__ proj,
                                               const float* __restrict__ pnw,
                                               const float* __restrict__ pnb,
                                               bf16* __restrict__ gated) {
    int r = blockIdx.x, tid = threadIdx.x;
    const bf16* row = xqw + (size_t)r * DM;
    float v0 = b2f(row[tid]), v1 = b2f(row[tid + 256]);
    float s = v0 + v1, q = v0 * v0 + v1 * v1;
#pragma unroll
    for (int off = 32; off; off >>= 1) {
        s += __shfl_xor(s, off);
        q += __shfl_xor(q, off);
    }
    __shared__ float sm[8];
    if ((tid & 63) == 0) { sm[tid >> 6] = s; sm[4 + (tid >> 6)] = q; }
    __syncthreads();
    s = sm[0] + sm[1] + sm[2] + sm[3];
    q = sm[4] + sm[5] + sm[6] + sm[7];
    float mu = s * (1.f / 512.f);
    float var = q * (1.f / 512.f) - mu * mu;
    float istd = rsqrtf(var + 1e-5f);
    const bf16* grow = proj + (size_t)r * PROJW + 1024;
    bf16* orow = gated + (size_t)r * DM;
#pragma unroll
    for (int e = 0; e < 2; ++e) {
        int c = tid + e * 256;
        float xv = (e == 0) ? v0 : v1;
        float nv = (xv - mu) * istd * pnw[c] + pnb[c];
        float g = b2f(grow[c]);
        float gg = 0.5f * g * (1.f + tanhf(0.7978845608028654f * (g + 0.044715f * g * g * g)));
        orow[c] = f2b(gg * nv);
    }
}

// ---------------------------------------------------------------- gq mean, two-phase
__global__ __launch_bounds__(256) void mean1_k(const float* __restrict__ gq,
                                               float* __restrict__ partial) {
    int blk = blockIdx.x;                 // 64 = (b:4)*(chunk:16)
    int b = blk >> 4, c = blk & 15;
    int tid = threadIdx.x;
    const float* p = gq + ((size_t)b * L_SEQ + c * 128) * DM + tid * 2;
    float a0 = 0.f, a1 = 0.f;
    for (int l = 0; l < 128; ++l) {
        float2 v = *(const float2*)(p + (size_t)l * DM);
        a0 += v.x; a1 += v.y;
    }
    partial[(size_t)blk * DM + tid * 2]     = a0;
    partial[(size_t)blk * DM + tid * 2 + 1] = a1;
}
__global__ __launch_bounds__(256) void mean2_k(const float* __restrict__ partial,
                                               float* __restrict__ gqm) {
    int t = blockIdx.x * 256 + threadIdx.x;
    if (t >= 2048) return;
    int b = t >> 9, d = t & 511;
    float acc = 0.f;
#pragma unroll
    for (int c = 0; c < 16; ++c) acc += partial[(size_t)(b * 16 + c) * DM + d];
    gqm[t] = acc * (1.f / 2048.f);
}

// ---------------------------------------------------------------- gain + final mix
__global__ __launch_bounds__(64) void final_k(const float* __restrict__ zl,
                                              const float* __restrict__ zt,
                                              const float* __restrict__ gk,
                                              const float* __restrict__ gqm,
                                              const float* __restrict__ alpha,
                                              const float* __restrict__ beta,
                                              float* __restrict__ out,
                                              float* __restrict__ gain_out) {
    int r = blockIdx.x;
    int lane = threadIdx.x;
    int b = r >> 11;
    const float* gkr = gk + (size_t)r * DM;
    const float* gmb = gqm + b * DM;
    float acc = 0.f;
#pragma unroll
    for (int i = 0; i < 8; ++i) acc = fmaf(gmb[lane + 64 * i], gkr[lane + 64 * i], acc);
#pragma unroll
    for (int off = 32; off; off >>= 1) acc += __shfl_xor(acc, off);
    float score = acc * 0.04419417382415922f;
    float g = sigmoidf_(alpha[0] * score + beta[0]);
    g = fminf(g, 0.55f);
    if (lane == 0) gain_out[r] = g;
    const float* zlr = zl + (size_t)r * DM;
    const float* ztr = zt + (size_t)r * DM;
    float* orow = out + (size_t)r * DM;
#pragma unroll
    for (int i = 0; i < 8; ++i) {
        int c = lane + 64 * i;
        float a = zlr[c];
        orow[c] = a + g * (ztr[c] - a);
    }
}

// ---------------------------------------------------------------- host launcher

extern "C" void kernel_launch(void* const* d_in, const int* in_sizes, int n_in,
                              void* d_out, int out_size, void* d_ws, size_t ws_size,
                              hipStream_t stream) {
    const float* x           = (const float*)d_in[0];
    const float* norm_w      = (const float*)d_in[1];
    const float* in_proj_w   = (const float*)d_in[2];
    const float* conv_w      = (const float*)d_in[3];
    const float* conv_b      = (const float*)d_in[4];
    const float* x_proj_w    = (const float*)d_in[5];
    const float* dt_head_w   = (const float*)d_in[6];
    const float* dt_head_b   = (const float*)d_in[7];
    const float* Dvec        = (const float*)d_in[8];
    const float* reduce_w    = (const float*)d_in[9];
    const float* q_net_w     = (const float*)d_in[10];
    const float* gain_q_w    = (const float*)d_in[11];
    const float* gain_k_w    = (const float*)d_in[12];
    const float* alpha       = (const float*)d_in[13];
    const float* beta        = (const float*)d_in[14];
    const float* qkv_w       = (const float*)d_in[15];
    const float* qkv_b       = (const float*)d_in[16];
    const float* ttt_lr_bias = (const float*)d_in[17];
    const float* W1          = (const float*)d_in[18];
    const float* b1          = (const float*)d_in[19];
    const float* token_idx   = (const float*)d_in[20];
    const float* token_bias  = (const float*)d_in[21];
    const float* ttt_ln_w    = (const float*)d_in[22];
    const float* ttt_ln_b    = (const float*)d_in[23];
    const float* post_norm_w = (const float*)d_in[24];
    const float* post_norm_b = (const float*)d_in[25];
    const float* wo_w        = (const float*)d_in[26];
    const float* wo_b        = (const float*)d_in[27];

    const size_t SZ_ROWDM = (size_t)NROWS * DM;
    const size_t MB = 1024u * 1024u;
    char* base = (char*)d_ws;

    float* out_p  = (float*)d_out;
    float* res_p  = out_p + SZ_ROWDM;
    float* gain_p = out_p + 2 * SZ_ROWDM;

    copy4_k<<<(int)(SZ_ROWDM / 4 / 256), 256, 0, stream>>>(
        (const float4*)x, (float4*)res_p, (int)(SZ_ROWDM / 4));

    if (ws_size < 116 * MB) return;

    // ---- workspace layout (MB offsets), peak < 115 MB
    bf16*  ws0   = (bf16*)base;                     // [0,7)    weight scratch bf16
    bf16*  xn    = (bf16*)(base + 7 * MB);          // [7,15)   xn -> conv side -> h_red
    bf16*  h_red = xn;
    bf16*  cside = (bf16*)(base + 7 * MB);          // conv boundary buffer (6.3MB, xn dead)
    bf16*  bufX  = (bf16*)(base + 16 * MB);         // [16,64)  xx/xb/y -> proj [16,41.3)
    bf16*  bufZ  = (bf16*)(base + 64 * MB);         // [64,112) z -> xqw/gated/chid
    float* xdbl  = (float*)(base + 112 * MB);       // [112,113.5)
    float* gqm   = (float*)(base + 113 * MB + 512 * 1024);
    float* mpart = (float*)(base + 114 * MB);       // 128 KB
    bf16*  proj  = bufX;
    bf16*  xqw   = bufZ;                            // [64,72)
    bf16*  gated = (bf16*)(base + 72 * MB);         // [72,80)
    bf16*  chid  = (bf16*)(base + 80 * MB);         // [80,88)
    float* zlong = (float*)(base + 88 * MB);        // [88,104)
    float* xkf   = (float*)(base + 42 * MB);        // [42,58) f32 xk per head (ttt)
    float* etav  = (float*)(base + 58 * MB);        // 256 KB
    float* k2s   = (float*)(base + 58 * MB + 512 * 1024);
    float* d13s  = (float*)(base + 59 * MB);
    float* zttt  = (float*)(base + 42 * MB);        // reuse xkf region after ttt
    float* gq    = (float*)(base + 16 * MB);        // proj dead by then
    float* gk    = (float*)(base + 64 * MB);        // xqw+gated dead by then

    // rmsnorm -> xn bf16
    rmsnorm_k<<<NROWS, 256, 0, stream>>>(x, norm_w, xn);

    // in_proj (both halves)
    cvt_k<<<(2 * DI * DM / 4 + 255) / 256, 256, 0, stream>>>(in_proj_w, ws0, 2 * DI * DM / 4);
    {
        dim3 g(NROWS / 128, DI / 128);
        gemm_mfma<0, bf16><<<g, 256, 0, stream>>>(xn, DM, ws0, DM, nullptr, bufX, DI, DI, DM);
        gemm_mfma<0, bf16><<<g, 256, 0, stream>>>(xn, DM, ws0 + (size_t)DI * DM, DM, nullptr, bufZ, DI, DI, DM);
    }

    // conv + silu in-place (parallel tiled; xn dead -> cside reuses its region)
    conv_boundary_k<<<((L_SEQ / CTILE - 1) * 2 * BDI) / 256, 256, 0, stream>>>(bufX, cside);
    conv_tile_k<<<((L_SEQ / CTILE) * BDI) / 256, 256, 0, stream>>>(bufX, cside, conv_w, conv_b);

    // x_proj -> xdbl f32
    cvt_k<<<(48 * DI / 4 + 255) / 256, 256, 0, stream>>>(x_proj_w, ws0, 48 * DI / 4);
    {
        dim3 g(NROWS / 128, 1);
        gemm_mfma<0, float><<<g, 256, 0, stream>>>(bufX, DI, ws0, DI, nullptr, xdbl, 48, 48, DI);
    }

    longhorn_k<<<(BATCH * DI) / 256, 256, 0, stream>>>(bufX, bufZ, xdbl, dt_head_w, dt_head_b, Dvec);

    // reduce -> h_red bf16
    cvt_k<<<(DM * DI / 4 + 255) / 256, 256, 0, stream>>>(reduce_w, ws0, DM * DI / 4);
    {
        dim3 g(NROWS / 128, DM / 128);
        gemm_mfma<0, bf16><<<g, 256, 0, stream>>>(bufX, DI, ws0, DI, nullptr, h_red, DM, DM, DI);
    }

    // qkv -> proj bf16
    cvt_k<<<(PROJW * DM / 4 + 255) / 256, 256, 0, stream>>>(qkv_w, ws0, PROJW * DM / 4);
    {
        dim3 g(NROWS / 128, (PROJW + 127) / 128);
        gemm_mfma<1, bf16><<<g, 256, 0, stream>>>(h_red, DM, ws0, DM, qkv_b, proj, PROJW, PROJW, DM);
    }

    // TTT prep + scan
    prep_ttt_k<<<32 * 16, 128, 0, stream>>>(proj, ttt_lr_bias, token_idx, token_bias,
                                            xkf, etav, k2s, d13s);
    ttt_k<<<BATCH * 8, 64, 0, stream>>>(proj, xkf, etav, k2s, d13s, W1, b1,
                                        ttt_ln_w, ttt_ln_b, xqw);

    gated_k<<<NROWS, 256, 0, stream>>>(xqw, proj, post_norm_w, post_norm_b, gated);

    // wo -> chid bf16
    cvt_k<<<(DM * DM / 4 + 255) / 256, 256, 0, stream>>>(wo_w, ws0, DM * DM / 4);
    {
        dim3 g(NROWS / 128, DM / 128);
        gemm_mfma<1, bf16><<<g, 256, 0, stream>>>(gated, DM, ws0, DM, wo_b, chid, DM, DM, DM);
    }

    // q_net: zlong (h_red), zttt (chid)
    cvt_k<<<(DM * DM / 4 + 255) / 256, 256, 0, stream>>>(q_net_w, ws0, DM * DM / 4);
    {
        dim3 g(NROWS / 128, DM / 128);
        gemm_mfma<0, float><<<g, 256, 0, stream>>>(h_red, DM, ws0, DM, nullptr, zlong, DM, DM, DM);
        gemm_mfma<0, float><<<g, 256, 0, stream>>>(chid, DM, ws0, DM, nullptr, zttt, DM, DM, DM);
    }

    // gain_q -> gq
    cvt_k<<<(DM * DM / 4 + 255) / 256, 256, 0, stream>>>(gain_q_w, ws0, DM * DM / 4);
    {
        dim3 g(NROWS / 128, DM / 128);
        gemm_mfma<0, float><<<g, 256, 0, stream>>>(h_red, DM, ws0, DM, nullptr, gq, DM, DM, DM);
    }
    // gain_k -> gk
    cvt_k<<<(DM * DM / 4 + 255) / 256, 256, 0, stream>>>(gain_k_w, ws0, DM * DM / 4);
    {
        dim3 g(NROWS / 128, DM / 128);
        gemm_mfma<0, float><<<g, 256, 0, stream>>>(h_red, DM, ws0, DM, nullptr, gk, DM, DM, DM);
    }

    mean1_k<<<64, 256, 0, stream>>>(gq, mpart);
    mean2_k<<<8, 256, 0, stream>>>(mpart, gqm);
    final_k<<<NROWS, 64, 0, stream>>>(zlong, zttt, gk, gqm, alpha, beta, out_p, gain_p);
}

// Round 5
// 4850.513 us; speedup vs baseline: 1.4153x; 1.1005x over previous
//
#include <hip/hip_runtime.h>
#include <hip/hip_bf16.h>
#include <cstdint>
#include <cstddef>

#define L_SEQ 2048
#define BATCH 4
#define DM    512
#define DI    3072
#define NROWS (BATCH * L_SEQ)   // 8192
#define PROJW 1544              // 3*512 + 8
#define CTILE 16
#define BDI   (BATCH * DI)      // 12288
#define TCH   64                // ttt chunk tokens
#define NCH   (L_SEQ / TCH)     // 32

using bf16 = __hip_bfloat16;

typedef __attribute__((ext_vector_type(8))) short short8v;
typedef __attribute__((ext_vector_type(4))) float f32x4;

// ---------------------------------------------------------------- utilities

__device__ __forceinline__ float sigmoidf_(float x) { return 1.f / (1.f + __expf(-x)); }
__device__ __forceinline__ float us2f(unsigned int u) {
    union { unsigned int i; float f; } c; c.i = u << 16; return c.f;
}
__device__ __forceinline__ bf16  f2b(float f) { return __float2bfloat16(f); }
__device__ __forceinline__ float b2f(bf16 v)  { return __bfloat162float(v); }
__device__ __forceinline__ void st1(float* p, float v) { *p = v; }
__device__ __forceinline__ void st1(bf16* p, float v)  { *p = f2b(v); }

// DPP-based wave64 sum -> uniform value (validated R4)
template <int CTRL>
__device__ __forceinline__ float dppadd_(float x) {
    int s = __builtin_amdgcn_update_dpp(0, __builtin_bit_cast(int, x), CTRL, 0xF, 0xF, true);
    return x + __builtin_bit_cast(float, s);
}
__device__ __forceinline__ float wave_sum_u(float x) {
    x = dppadd_<0x111>(x);   // row_shr:1
    x = dppadd_<0x112>(x);   // row_shr:2
    x = dppadd_<0x114>(x);   // row_shr:4
    x = dppadd_<0x118>(x);   // row_shr:8
    x = dppadd_<0x142>(x);   // row_bcast:15
    x = dppadd_<0x143>(x);   // row_bcast:31  -> total in lane 63
    return __builtin_bit_cast(float,
        __builtin_amdgcn_readlane(__builtin_bit_cast(int, x), 63));
}

// ---------------------------------------------------------------- residual copy
__global__ __launch_bounds__(256) void copy4_k(const float4* __restrict__ in,
                                               float4* __restrict__ out, int n) {
    int i = blockIdx.x * 256 + threadIdx.x;
    if (i < n) out[i] = in[i];
}

// ---------------------------------------------------------------- f32 -> bf16 weight convert
__global__ __launch_bounds__(256) void cvt_k(const float* __restrict__ in,
                                             bf16* __restrict__ out, int n4) {
    int i = blockIdx.x * 256 + threadIdx.x;
    if (i >= n4) return;
    float4 v = ((const float4*)in)[i];
    out[4 * i + 0] = f2b(v.x);
    out[4 * i + 1] = f2b(v.y);
    out[4 * i + 2] = f2b(v.z);
    out[4 * i + 3] = f2b(v.w);
}

// ---------------------------------------------------------------- rmsnorm (row=512) -> bf16
__global__ __launch_bounds__(256) void rmsnorm_k(const float* __restrict__ x,
                                                 const float* __restrict__ w,
                                                 bf16* __restrict__ xn) {
    int r = blockIdx.x, tid = threadIdx.x;
    const float* row = x + (size_t)r * DM;
    float v0 = row[tid], v1 = row[tid + 256];
    float q = v0 * v0 + v1 * v1;
#pragma unroll
    for (int off = 32; off; off >>= 1) q += __shfl_xor(q, off);
    __shared__ float sm[4];
    if ((tid & 63) == 0) sm[tid >> 6] = q;
    __syncthreads();
    q = sm[0] + sm[1] + sm[2] + sm[3];
    float scale = rsqrtf(q * (1.f / 512.f) + 1e-5f);
    bf16* orow = xn + (size_t)r * DM;
    orow[tid]       = f2b(v0 * scale * w[tid]);
    orow[tid + 256] = f2b(v1 * scale * w[tid + 256]);
}

// ---------------------------------------------------------------- bf16 MFMA GEMM (validated R3)
template <int BIAS, typename TC>
__global__ __launch_bounds__(256) void gemm_mfma(const bf16* __restrict__ A, int lda,
                                                 const bf16* __restrict__ Wb, int ldw,
                                                 const float* __restrict__ bias,
                                                 TC* __restrict__ C, int ldc,
                                                 int N, int K) {
    __shared__ __align__(16) bf16 As[128 * 48];
    __shared__ __align__(16) bf16 Ws[128 * 48];
    const int tid = threadIdx.x;
    const int lane = tid & 63;
    const int widx = tid >> 6;
    const int bm = blockIdx.x * 128;
    const int bn = blockIdx.y * 128;
    const int wr = (widx >> 1) * 64;
    const int wc = (widx & 1) * 64;

    f32x4 acc[4][4];
#pragma unroll
    for (int i = 0; i < 4; ++i)
#pragma unroll
        for (int j = 0; j < 4; ++j) acc[i][j] = (f32x4){0.f, 0.f, 0.f, 0.f};

    const int r0 = tid >> 2;
    const int c0 = tid & 3;
    const int frow = lane & 15;
    const int fk = (lane >> 4) * 8;

    int n0 = bn + r0;       if (n0 > N - 1) n0 = N - 1;
    int n1 = bn + r0 + 64;  if (n1 > N - 1) n1 = N - 1;
    const bf16* pa0 = A + (size_t)(bm + r0) * lda + c0 * 8;
    const bf16* pa1 = A + (size_t)(bm + r0 + 64) * lda + c0 * 8;
    const bf16* pb0 = Wb + (size_t)n0 * ldw + c0 * 8;
    const bf16* pb1 = Wb + (size_t)n1 * ldw + c0 * 8;

    for (int k0 = 0; k0 < K; k0 += 32) {
        short8v a0 = *(const short8v*)(pa0 + k0);
        short8v a1 = *(const short8v*)(pa1 + k0);
        short8v b0 = *(const short8v*)(pb0 + k0);
        short8v b1 = *(const short8v*)(pb1 + k0);
        __syncthreads();
        *(short8v*)&As[r0 * 48 + c0 * 8] = a0;
        *(short8v*)&As[(r0 + 64) * 48 + c0 * 8] = a1;
        *(short8v*)&Ws[r0 * 48 + c0 * 8] = b0;
        *(short8v*)&Ws[(r0 + 64) * 48 + c0 * 8] = b1;
        __syncthreads();
        short8v af[4], bg[4];
#pragma unroll
        for (int mi = 0; mi < 4; ++mi)
            af[mi] = *(const short8v*)&As[(wr + mi * 16 + frow) * 48 + fk];
#pragma unroll
        for (int ni = 0; ni < 4; ++ni)
            bg[ni] = *(const short8v*)&Ws[(wc + ni * 16 + frow) * 48 + fk];
#pragma unroll
        for (int mi = 0; mi < 4; ++mi)
#pragma unroll
            for (int ni = 0; ni < 4; ++ni)
                acc[mi][ni] = __builtin_amdgcn_mfma_f32_16x16x32_bf16(
                    af[mi], bg[ni], acc[mi][ni], 0, 0, 0);
    }

#pragma unroll
    for (int ni = 0; ni < 4; ++ni) {
        int col = bn + wc + ni * 16 + (lane & 15);
        if (col < N) {
            float bz = BIAS ? bias[col] : 0.f;
#pragma unroll
            for (int mi = 0; mi < 4; ++mi) {
                int rbase = bm + wr + mi * 16 + (lane >> 4) * 4;
#pragma unroll
                for (int r = 0; r < 4; ++r) {
                    float v = acc[mi][ni][r] + bz;
                    st1(&C[(size_t)(rbase + r) * ldc + col], v);
                }
            }
        }
    }
}

// ---------------------------------------------------------------- conv: boundary row copy
__global__ __launch_bounds__(256) void conv_boundary_k(const bf16* __restrict__ x,
                                                       bf16* __restrict__ side) {
    int idx = blockIdx.x * 256 + threadIdx.x;
    const int total = (L_SEQ / CTILE - 1) * 2 * BDI;
    if (idx >= total) return;
    int col = idx % BDI;
    int rr = idx / BDI;
    int tile = (rr >> 1) + 1;
    int r = rr & 1;
    int b = col / DI, d = col % DI;
    int l = tile * CTILE - 2 + r;
    side[idx] = x[((size_t)b * L_SEQ + l) * DI + d];
}

// ---------------------------------------------------------------- conv tile: causal depthwise conv3 + silu
__global__ __launch_bounds__(256) void conv_tile_k(bf16* __restrict__ x,
                                                   const bf16* __restrict__ side,
                                                   const float* __restrict__ cw,
                                                   const float* __restrict__ cb) {
    int idx = blockIdx.x * 256 + threadIdx.x;
    const int total = (L_SEQ / CTILE) * BDI;
    if (idx >= total) return;
    int col = idx % BDI;
    int tile = idx / BDI;
    int b = col / DI, d = col % DI;
    float w0 = cw[3 * d], w1 = cw[3 * d + 1], w2 = cw[3 * d + 2], bias = cb[d];
    size_t base = ((size_t)b * L_SEQ + tile * CTILE) * DI + d;
    float xm2, xm1;
    if (tile == 0) { xm2 = 0.f; xm1 = 0.f; }
    else {
        const bf16* sp = side + ((size_t)(tile - 1) * 2) * BDI + col;
        xm2 = b2f(sp[0]);
        xm1 = b2f(sp[BDI]);
    }
    float cur = b2f(x[base]);
#pragma unroll
    for (int i = 0; i < CTILE; ++i) {
        float nxt = (i + 1 < CTILE) ? b2f(x[base + (size_t)(i + 1) * DI]) : 0.f;
        float a = bias + w0 * xm2 + w1 * xm1 + w2 * cur;
        x[base + (size_t)i * DI] = f2b(a * sigmoidf_(a));
        xm2 = xm1; xm1 = cur; cur = nxt;
    }
}

// ---------------------------------------------------------------- longhorn selective scan (validated R3)
__global__ __launch_bounds__(256) void longhorn_k(bf16* __restrict__ xb_y,
                                                  const bf16* __restrict__ z,
                                                  const float* __restrict__ xdbl,
                                                  const float* __restrict__ dtw,
                                                  const float* __restrict__ dtb_v,
                                                  const float* __restrict__ Dv) {
    int tid = blockIdx.x * 256 + threadIdx.x;
    int b = tid / DI;
    int d = tid % DI;
    float w32[32];
#pragma unroll
    for (int i = 0; i < 32; ++i) w32[i] = dtw[d * 32 + i];
    float s[8] = {0.f, 0.f, 0.f, 0.f, 0.f, 0.f, 0.f, 0.f};
    float dtb = dtb_v[d], Dd = Dv[d];
    size_t rbase = (size_t)b * L_SEQ * DI + d;
    const float* xdb = xdbl + (size_t)b * L_SEQ * 48;

    float xv = b2f(xb_y[rbase]);
    float zv = b2f(z[rbase]);

    for (int t = 0; t < L_SEQ; ++t) {
        float x_c = xv, z_c = zv;
        if (t + 1 < L_SEQ) {
            size_t nidx = rbase + (size_t)(t + 1) * DI;
            xv = b2f(xb_y[nidx]);
            zv = b2f(z[nidx]);
        }
        const float* row = xdb + (size_t)t * 48;
        float dt_c = 0.f;
#pragma unroll
        for (int i = 0; i < 32; i += 4) {
            float4 r4 = *(const float4*)(row + i);
            dt_c = fmaf(r4.x, w32[i + 0], dt_c);
            dt_c = fmaf(r4.y, w32[i + 1], dt_c);
            dt_c = fmaf(r4.z, w32[i + 2], dt_c);
            dt_c = fmaf(r4.w, w32[i + 3], dt_c);
        }
        float kq[16];
#pragma unroll
        for (int i = 0; i < 16; i += 4) *(float4*)&kq[i] = *(const float4*)(row + 32 + i);

        float sig = sigmoidf_(dt_c + dtb);
        float ksq = 0.f;
#pragma unroll
        for (int n = 0; n < 8; ++n) ksq = fmaf(kq[n], kq[n], ksq);
        float dts = sig / (1.f + sig * ksq);
        float y = 0.f;
#pragma unroll
        for (int n = 0; n < 8; ++n) {
            float dB = dts * kq[n];
            s[n] = s[n] * (1.f - dB * kq[n]) + x_c * dB;
            y = fmaf(s[n], kq[8 + n], y);
        }
        y = fmaf(Dd, x_c, y);
        float out = y * (z_c * sigmoidf_(z_c));
        xb_y[rbase + (size_t)t * DI] = f2b(out);
    }
}

// ---------------------------------------------------------------- TTT prep (validated R4)
__global__ __launch_bounds__(128) void prep_ttt_k(const bf16* __restrict__ proj,
                                                  const float* __restrict__ lr_bias,
                                                  const float* __restrict__ tok_idx,
                                                  const float* __restrict__ tok_bias,
                                                  float* __restrict__ xkf,
                                                  float* __restrict__ etav,
                                                  float* __restrict__ k2s,
                                                  float* __restrict__ d13s) {
    int bh = blockIdx.x >> 4;
    int t = (blockIdx.x & 15) * 128 + threadIdx.x;
    int b = bh >> 3, h = bh & 7;
    const bf16* prow = proj + ((size_t)b * L_SEQ + t) * PROJW;
    const bf16* pk = prow + h * 64;
    float v[64];
    float k2 = 0.f;
#pragma unroll
    for (int i = 0; i < 64; i += 8) {
        short8v s = *(const short8v*)(pk + i);
#pragma unroll
        for (int j = 0; j < 8; ++j) {
            float f = us2f((unsigned short)s[j]);
            v[i + j] = f;
            k2 = fmaf(f, f, k2);
        }
    }
    float* xo = xkf + ((size_t)bh * L_SEQ + t) * 64;
#pragma unroll
    for (int i = 0; i < 64; i += 4)
        *(float4*)(xo + i) = make_float4(v[i], v[i + 1], v[i + 2], v[i + 3]);

    int tn = (t + 1 < L_SEQ) ? t + 1 : t;
    const bf16* pn = proj + ((size_t)b * L_SEQ + tn) * PROJW + h * 64;
    float d13 = 0.f;
#pragma unroll
    for (int i = 0; i < 64; i += 8) {
        short8v s = *(const short8v*)(pn + i);
#pragma unroll
        for (int j = 0; j < 8; ++j) d13 = fmaf(us2f((unsigned short)s[j]), v[i + j], d13);
    }
    float eta = sigmoidf_(b2f(prow[1536 + h]) + lr_bias[h]) *
                fmaxf(tok_idx[t] + tok_bias[t], 0.f);
    size_t o = (size_t)bh * L_SEQ + t;
    etav[o] = eta;
    k2s[o]  = k2;
    d13s[o] = d13;
}

// ---------------------------------------------------------------- TTT scan v5: LDS chunk staging (latency amortized)
// one wave per (b,h). lane g owns W[:,g]. All per-token reads from LDS.
// Double-buffered 64-token chunks; reg-staged global loads issued ~1.5 chunks ahead.
__global__ __launch_bounds__(64) void ttt_k(const bf16* __restrict__ proj,
                                            const float* __restrict__ xkf,
                                            const float* __restrict__ etav,
                                            const float* __restrict__ k2s,
                                            const float* __restrict__ d13s,
                                            const float* __restrict__ W1,
                                            const float* __restrict__ b1,
                                            const float* __restrict__ ln_w,
                                            const float* __restrict__ ln_b,
                                            bf16* __restrict__ xqw) {
    const int lane = threadIdx.x;
    const int bh = blockIdx.x;
    const int b = bh >> 3, h = bh & 7;

    __shared__ __align__(16) float xkb[2][TCH][64];   // 32 KB
    __shared__ __align__(16) bf16  xvb[2][TCH][64];   // 16 KB
    __shared__ float sco[2][3][TCH];                  // 1.5 KB

    float W[64];
#pragma unroll
    for (int f = 0; f < 64; ++f) W[f] = W1[(size_t)(h * 64 + f) * 64 + lane];
    float bvec = b1[h * 64 + lane];
    float lw = ln_w[h * 64 + lane];
    float lb = ln_b[h * 64 + lane];
    float p = lw * lw;
    float P0 = wave_sum_u(p);

    const float* kfg = xkf + (size_t)bh * L_SEQ * 64;
    const bf16*  pvg = proj + (size_t)b * L_SEQ * PROJW + 512 + h * 64;
    const float* evg = etav + (size_t)bh * L_SEQ;
    const float* k2g = k2s + (size_t)bh * L_SEQ;
    const float* dvg = d13s + (size_t)bh * L_SEQ;

    const int xr4 = lane >> 4, xc4 = lane & 15;   // xk staging: 4 rows / load
    const int vr8 = lane >> 3, vc8 = lane & 7;    // xv staging: 8 rows / load

    float4  lk[16];
    short8v lv[8];
    float   ls0, ls1, ls2;

    auto issue_loads = [&](int c) {
        const int t0 = c * TCH;
#pragma unroll
        for (int i = 0; i < 16; ++i)
            lk[i] = *(const float4*)(kfg + (size_t)(t0 + 4 * i + xr4) * 64 + xc4 * 4);
#pragma unroll
        for (int i = 0; i < 8; ++i)
            lv[i] = *(const short8v*)(pvg + (size_t)(t0 + 8 * i + vr8) * PROJW + vc8 * 8);
        ls0 = evg[t0 + lane];
        ls1 = k2g[t0 + lane];
        ls2 = dvg[t0 + lane];
    };
    auto write_lds = [&](int bi) {
#pragma unroll
        for (int i = 0; i < 16; ++i)
            *(float4*)&xkb[bi][4 * i + xr4][xc4 * 4] = lk[i];
#pragma unroll
        for (int i = 0; i < 8; ++i)
            *(short8v*)&xvb[bi][8 * i + vr8][vc8 * 8] = lv[i];
        sco[bi][0][lane] = ls0;
        sco[bi][1][lane] = ls1;
        sco[bi][2][lane] = ls2;
    };

    xkb[1][TCH - 1][lane] = 0.f;   // guard: c=0 kp row (c1p=0, but avoid NaN garbage)

    issue_loads(0);
    write_lds(0);
    issue_loads(1);

    // m1 = xk_0 @ W + b
    float m1;
    {
        const float4* k4 = (const float4*)xkb[0][0];
        float a0 = 0.f, a1 = 0.f, a2 = 0.f, a3 = 0.f;
#pragma unroll
        for (int f = 0; f < 16; ++f) {
            float4 kv = k4[f];
            a0 = fmaf(kv.x, W[4 * f + 0], a0);
            a1 = fmaf(kv.y, W[4 * f + 1], a1);
            a2 = fmaf(kv.z, W[4 * f + 2], a2);
            a3 = fmaf(kv.w, W[4 * f + 3], a3);
        }
        m1 = (a0 + a1) + (a2 + a3) + bvec;
    }

    float corr = 0.f, c1p = 0.f;
    bf16* xq = xqw + ((size_t)b * L_SEQ) * DM + h * 64 + lane;

    for (int c = 0; c < NCH; ++c) {
        const int cur = c & 1;
        for (int local = 0; local < TCH; ++local) {
            if (local == 32) {   // uniform branch: stage next chunk, prefetch chunk+2
                if (c + 1 < NCH) write_lds(1 - cur);
                if (c + 2 < NCH) issue_loads(c + 2);
            }
            // buf[1-cur]: read row63 @local0 (prev chunk) < overwrite @local32 < read row0 @local63 (next chunk)
            const float* kp = (local == 0) ? xkb[1 - cur][TCH - 1] : xkb[cur][local - 1];
            const float* kn = (local == TCH - 1) ? xkb[1 - cur][0] : xkb[cur][local + 1];
            float xk_c = xkb[cur][local][lane];
            float xv_c = b2f(xvb[cur][local][lane]);
            float eta  = sco[cur][0][local];
            float k2u  = sco[cur][1][local];
            float d13u = sco[cur][2][local];

            float z1 = m1 - corr;
            float q = (lb - xv_c + xk_c) * lw;
            float S1  = wave_sum_u(z1);
            float S2  = wave_sum_u(z1 * z1);
            float PZ1 = wave_sum_u(p * z1);
            float PZ2 = wave_sum_u(p * z1 * z1);
            float Q0  = wave_sum_u(q);
            float Q1  = wave_sum_u(q * z1);

            // fused W update (token t-1) + matvec for token t+1 (LDS broadcast reads)
            float m1n;
            {
                const float4* kp4 = (const float4*)kp;
                const float4* kn4 = (const float4*)kn;
                float a0 = 0.f, a1 = 0.f, a2 = 0.f, a3 = 0.f;
#pragma unroll
                for (int f = 0; f < 16; ++f) {
                    float4 kpv = kp4[f];
                    float4 knv = kn4[f];
                    float w0 = fmaf(-c1p, kpv.x, W[4 * f + 0]); W[4 * f + 0] = w0; a0 = fmaf(knv.x, w0, a0);
                    float w1 = fmaf(-c1p, kpv.y, W[4 * f + 1]); W[4 * f + 1] = w1; a1 = fmaf(knv.y, w1, a1);
                    float w2 = fmaf(-c1p, kpv.z, W[4 * f + 2]); W[4 * f + 2] = w2; a2 = fmaf(knv.z, w2, a2);
                    float w3 = fmaf(-c1p, kpv.w, W[4 * f + 3]); W[4 * f + 3] = w3; a3 = fmaf(knv.w, w3, a3);
                }
                bvec -= c1p;
                m1n = (a0 + a1) + (a2 + a3) + bvec;
            }

            // scalar LN-backward algebra (validated identities)
            float mu = S1 * 0.015625f;
            float var = fmaf(S2, 0.015625f, -mu * mu);
            float istd = rsqrtf(var + 1e-6f);
            float A_ = fmaf(istd, PZ1 - mu * P0, Q0);
            float Bv = istd * istd * (PZ2 - 2.f * mu * PZ1 + mu * mu * P0) + istd * (Q1 - mu * Q0);
            float xh = (z1 - mu) * istd;
            float gxh = fmaf(p, xh, q);
            float grad = (64.f * gxh - A_ - xh * Bv) * (istd * 0.015625f);
            float z1q = z1 - eta * (k2u + 1.f) * grad;

            float dq = z1q - mu;
            float SQ = wave_sum_u(dq * dq);
            float istd2 = rsqrtf(fmaf(SQ, 0.015625f, 1e-6f));
            float outv = fmaf(lw, dq * istd2, xk_c + lb);
            xq[(size_t)(c * TCH + local) * DM] = f2b(outv);

            float eg = eta * grad;
            corr = eg * (d13u + 1.f);
            c1p = eg;
            m1 = m1n;
        }
    }
}

// ---------------------------------------------------------------- post-norm + gelu gate
__global__ __launch_bounds__(256) void gated_k(const bf16* __restrict__ xqw,
                                               const bf16* __restrict__ proj,
                                               const float* __restrict__ pnw,
                                               const float* __restrict__ pnb,
                                               bf16* __restrict__ gated) {
    int r = blockIdx.x, tid = threadIdx.x;
    const bf16* row = xqw + (size_t)r * DM;
    float v0 = b2f(row[tid]), v1 = b2f(row[tid + 256]);
    float s = v0 + v1, q = v0 * v0 + v1 * v1;
#pragma unroll
    for (int off = 32; off; off >>= 1) {
        s += __shfl_xor(s, off);
        q += __shfl_xor(q, off);
    }
    __shared__ float sm[8];
    if ((tid & 63) == 0) { sm[tid >> 6] = s; sm[4 + (tid >> 6)] = q; }
    __syncthreads();
    s = sm[0] + sm[1] + sm[2] + sm[3];
    q = sm[4] + sm[5] + sm[6] + sm[7];
    float mu = s * (1.f / 512.f);
    float var = q * (1.f / 512.f) - mu * mu;
    float istd = rsqrtf(var + 1e-5f);
    const bf16* grow = proj + (size_t)r * PROJW + 1024;
    bf16* orow = gated + (size_t)r * DM;
#pragma unroll
    for (int e = 0; e < 2; ++e) {
        int c = tid + e * 256;
        float xv = (e == 0) ? v0 : v1;
        float nv = (xv - mu) * istd * pnw[c] + pnb[c];
        float g = b2f(grow[c]);
        float gg = 0.5f * g * (1.f + tanhf(0.7978845608028654f * (g + 0.044715f * g * g * g)));
        orow[c] = f2b(gg * nv);
    }
}

// ---------------------------------------------------------------- gq mean, two-phase
__global__ __launch_bounds__(256) void mean1_k(const float* __restrict__ gq,
                                               float* __restrict__ partial) {
    int blk = blockIdx.x;
    int b = blk >> 4, c = blk & 15;
    int tid = threadIdx.x;
    const float* p = gq + ((size_t)b * L_SEQ + c * 128) * DM + tid * 2;
    float a0 = 0.f, a1 = 0.f;
    for (int l = 0; l < 128; ++l) {
        float2 v = *(const float2*)(p + (size_t)l * DM);
        a0 += v.x; a1 += v.y;
    }
    partial[(size_t)blk * DM + tid * 2]     = a0;
    partial[(size_t)blk * DM + tid * 2 + 1] = a1;
}
__global__ __launch_bounds__(256) void mean2_k(const float* __restrict__ partial,
                                               float* __restrict__ gqm) {
    int t = blockIdx.x * 256 + threadIdx.x;
    if (t >= 2048) return;
    int b = t >> 9, d = t & 511;
    float acc = 0.f;
#pragma unroll
    for (int c = 0; c < 16; ++c) acc += partial[(size_t)(b * 16 + c) * DM + d];
    gqm[t] = acc * (1.f / 2048.f);
}

// ---------------------------------------------------------------- gain + final mix
__global__ __launch_bounds__(64) void final_k(const float* __restrict__ zl,
                                              const float* __restrict__ zt,
                                              const float* __restrict__ gk,
                                              const float* __restrict__ gqm,
                                              const float* __restrict__ alpha,
                                              const float* __restrict__ beta,
                                              float* __restrict__ out,
                                              float* __restrict__ gain_out) {
    int r = blockIdx.x;
    int lane = threadIdx.x;
    int b = r >> 11;
    const float* gkr = gk + (size_t)r * DM;
    const float* gmb = gqm + b * DM;
    float acc = 0.f;
#pragma unroll
    for (int i = 0; i < 8; ++i) acc = fmaf(gmb[lane + 64 * i], gkr[lane + 64 * i], acc);
#pragma unroll
    for (int off = 32; off; off >>= 1) acc += __shfl_xor(acc, off);
    float score = acc * 0.04419417382415922f;
    float g = sigmoidf_(alpha[0] * score + beta[0]);
    g = fminf(g, 0.55f);
    if (lane == 0) gain_out[r] = g;
    const float* zlr = zl + (size_t)r * DM;
    const float* ztr = zt + (size_t)r * DM;
    float* orow = out + (size_t)r * DM;
#pragma unroll
    for (int i = 0; i < 8; ++i) {
        int c = lane + 64 * i;
        float a = zlr[c];
        orow[c] = a + g * (ztr[c] - a);
    }
}

// ---------------------------------------------------------------- host launcher

extern "C" void kernel_launch(void* const* d_in, const int* in_sizes, int n_in,
                              void* d_out, int out_size, void* d_ws, size_t ws_size,
                              hipStream_t stream) {
    const float* x           = (const float*)d_in[0];
    const float* norm_w      = (const float*)d_in[1];
    const float* in_proj_w   = (const float*)d_in[2];
    const float* conv_w      = (const float*)d_in[3];
    const float* conv_b      = (const float*)d_in[4];
    const float* x_proj_w    = (const float*)d_in[5];
    const float* dt_head_w   = (const float*)d_in[6];
    const float* dt_head_b   = (const float*)d_in[7];
    const float* Dvec        = (const float*)d_in[8];
    const float* reduce_w    = (const float*)d_in[9];
    const float* q_net_w     = (const float*)d_in[10];
    const float* gain_q_w    = (const float*)d_in[11];
    const float* gain_k_w    = (const float*)d_in[12];
    const float* alpha       = (const float*)d_in[13];
    const float* beta        = (const float*)d_in[14];
    const float* qkv_w       = (const float*)d_in[15];
    const float* qkv_b       = (const float*)d_in[16];
    const float* ttt_lr_bias = (const float*)d_in[17];
    const float* W1          = (const float*)d_in[18];
    const float* b1          = (const float*)d_in[19];
    const float* token_idx   = (const float*)d_in[20];
    const float* token_bias  = (const float*)d_in[21];
    const float* ttt_ln_w    = (const float*)d_in[22];
    const float* ttt_ln_b    = (const float*)d_in[23];
    const float* post_norm_w = (const float*)d_in[24];
    const float* post_norm_b = (const float*)d_in[25];
    const float* wo_w        = (const float*)d_in[26];
    const float* wo_b        = (const float*)d_in[27];

    const size_t SZ_ROWDM = (size_t)NROWS * DM;
    const size_t MB = 1024u * 1024u;
    char* base = (char*)d_ws;

    float* out_p  = (float*)d_out;
    float* res_p  = out_p + SZ_ROWDM;
    float* gain_p = out_p + 2 * SZ_ROWDM;

    copy4_k<<<(int)(SZ_ROWDM / 4 / 256), 256, 0, stream>>>(
        (const float4*)x, (float4*)res_p, (int)(SZ_ROWDM / 4));

    if (ws_size < 116 * MB) return;

    // ---- workspace layout (MB offsets), peak < 115 MB
    bf16*  ws0   = (bf16*)base;                     // [0,7)    weight scratch bf16
    bf16*  xn    = (bf16*)(base + 7 * MB);          // [7,15)   xn -> conv side -> h_red
    bf16*  h_red = xn;
    bf16*  cside = (bf16*)(base + 7 * MB);
    bf16*  bufX  = (bf16*)(base + 16 * MB);         // [16,64)  xx/xb/y -> proj
    bf16*  bufZ  = (bf16*)(base + 64 * MB);         // [64,112) z -> xqw/gated/chid
    float* xdbl  = (float*)(base + 112 * MB);
    float* gqm   = (float*)(base + 113 * MB + 512 * 1024);
    float* mpart = (float*)(base + 114 * MB);
    bf16*  proj  = bufX;
    bf16*  xqw   = bufZ;                            // [64,72)
    bf16*  gated = (bf16*)(base + 72 * MB);
    bf16*  chid  = (bf16*)(base + 80 * MB);
    float* zlong = (float*)(base + 88 * MB);        // [88,104)
    float* xkf   = (float*)(base + 42 * MB);        // [42,58)
    float* etav  = (float*)(base + 58 * MB);
    float* k2s   = (float*)(base + 58 * MB + 512 * 1024);
    float* d13s  = (float*)(base + 59 * MB);
    float* zttt  = (float*)(base + 42 * MB);        // reuse after ttt
    float* gq    = (float*)(base + 16 * MB);
    float* gk    = (float*)(base + 64 * MB);

    rmsnorm_k<<<NROWS, 256, 0, stream>>>(x, norm_w, xn);

    cvt_k<<<(2 * DI * DM / 4 + 255) / 256, 256, 0, stream>>>(in_proj_w, ws0, 2 * DI * DM / 4);
    {
        dim3 g(NROWS / 128, DI / 128);
        gemm_mfma<0, bf16><<<g, 256, 0, stream>>>(xn, DM, ws0, DM, nullptr, bufX, DI, DI, DM);
        gemm_mfma<0, bf16><<<g, 256, 0, stream>>>(xn, DM, ws0 + (size_t)DI * DM, DM, nullptr, bufZ, DI, DI, DM);
    }

    conv_boundary_k<<<((L_SEQ / CTILE - 1) * 2 * BDI) / 256, 256, 0, stream>>>(bufX, cside);
    conv_tile_k<<<((L_SEQ / CTILE) * BDI) / 256, 256, 0, stream>>>(bufX, cside, conv_w, conv_b);

    cvt_k<<<(48 * DI / 4 + 255) / 256, 256, 0, stream>>>(x_proj_w, ws0, 48 * DI / 4);
    {
        dim3 g(NROWS / 128, 1);
        gemm_mfma<0, float><<<g, 256, 0, stream>>>(bufX, DI, ws0, DI, nullptr, xdbl, 48, 48, DI);
    }

    longhorn_k<<<(BATCH * DI) / 256, 256, 0, stream>>>(bufX, bufZ, xdbl, dt_head_w, dt_head_b, Dvec);

    cvt_k<<<(DM * DI / 4 + 255) / 256, 256, 0, stream>>>(reduce_w, ws0, DM * DI / 4);
    {
        dim3 g(NROWS / 128, DM / 128);
        gemm_mfma<0, bf16><<<g, 256, 0, stream>>>(bufX, DI, ws0, DI, nullptr, h_red, DM, DM, DI);
    }

    cvt_k<<<(PROJW * DM / 4 + 255) / 256, 256, 0, stream>>>(qkv_w, ws0, PROJW * DM / 4);
    {
        dim3 g(NROWS / 128, (PROJW + 127) / 128);
        gemm_mfma<1, bf16><<<g, 256, 0, stream>>>(h_red, DM, ws0, DM, qkv_b, proj, PROJW, PROJW, DM);
    }

    prep_ttt_k<<<32 * 16, 128, 0, stream>>>(proj, ttt_lr_bias, token_idx, token_bias,
                                            xkf, etav, k2s, d13s);
    ttt_k<<<BATCH * 8, 64, 0, stream>>>(proj, xkf, etav, k2s, d13s, W1, b1,
                                        ttt_ln_w, ttt_ln_b, xqw);

    gated_k<<<NROWS, 256, 0, stream>>>(xqw, proj, post_norm_w, post_norm_b, gated);

    cvt_k<<<(DM * DM / 4 + 255) / 256, 256, 0, stream>>>(wo_w, ws0, DM * DM / 4);
    {
        dim3 g(NROWS / 128, DM / 128);
        gemm_mfma<1, bf16><<<g, 256, 0, stream>>>(gated, DM, ws0, DM, wo_b, chid, DM, DM, DM);
    }

    cvt_k<<<(DM * DM / 4 + 255) / 256, 256, 0, stream>>>(q_net_w, ws0, DM * DM / 4);
    {
        dim3 g(NROWS / 128, DM / 128);
        gemm_mfma<0, float><<<g, 256, 0, stream>>>(h_red, DM, ws0, DM, nullptr, zlong, DM, DM, DM);
        gemm_mfma<0, float><<<g, 256, 0, stream>>>(chid, DM, ws0, DM, nullptr, zttt, DM, DM, DM);
    }

    cvt_k<<<(DM * DM / 4 + 255) / 256, 256, 0, stream>>>(gain_q_w, ws0, DM * DM / 4);
    {
        dim3 g(NROWS / 128, DM / 128);
        gemm_mfma<0, float><<<g, 256, 0, stream>>>(h_red, DM, ws0, DM, nullptr, gq, DM, DM, DM);
    }
    cvt_k<<<(DM * DM / 4 + 255) / 256, 256, 0, stream>>>(gain_k_w, ws0, DM * DM / 4);
    {
        dim3 g(NROWS / 128, DM / 128);
        gemm_mfma<0, float><<<g, 256, 0, stream>>>(h_red, DM, ws0, DM, nullptr, gk, DM, DM, DM);
    }

    mean1_k<<<64, 256, 0, stream>>>(gq, mpart);
    mean2_k<<<8, 256, 0, stream>>>(mpart, gqm);
    final_k<<<NROWS, 64, 0, stream>>>(zlong, zttt, gk, gqm, alpha, beta, out_p, gain_p);
}